// Round 6
// baseline (19867.723 us; speedup 1.0000x reference)
//
#include <hip/hip_runtime.h>
#include <hip/hip_bf16.h>
#include <hip/hip_cooperative_groups.h>

namespace cg = cooperative_groups;

#define EPSF 1e-5f

typedef unsigned short u16;
typedef unsigned int   u32;
typedef __attribute__((ext_vector_type(8))) short short8;
typedef __attribute__((ext_vector_type(4))) float f32x4;

constexpr int B  = 256;
constexpr int T  = 128;
constexpr int H  = 1024;
constexpr int INNER = 3 * H;   // 3072
constexpr int BT = B * T;      // 32768
constexpr int NZ = 2 * H;      // 2048

__device__ inline u16 f2bf(float v) {
    u32 u = __float_as_uint(v);
    return (u16)((u + 0x7fffu + ((u >> 16) & 1u)) >> 16);
}
__device__ inline float bf2f(u16 h) { return __uint_as_float(((u32)h) << 16); }

// ---------- one-time: transpose fp32 [1024][3072] -> split bf16 [3072][1024] ----------
__global__ __launch_bounds__(256)
void transpose_split(const float* __restrict__ src, u16* __restrict__ dhi, u16* __restrict__ dlo)
{
    __shared__ float tile[32][33];
    const int tx = threadIdx.x & 31, ty = threadIdx.x >> 5;
    const int bx = blockIdx.x, by = blockIdx.y;
    #pragma unroll
    for (int i = 0; i < 4; ++i)
        tile[ty + i * 8][tx] = src[(size_t)(by * 32 + ty + i * 8) * INNER + bx * 32 + tx];
    __syncthreads();
    #pragma unroll
    for (int i = 0; i < 4; ++i) {
        int n = bx * 32 + ty + i * 8;
        int k = by * 32 + tx;
        float v = tile[tx][ty + i * 8];
        u16 hi = f2bf(v);
        dhi[(size_t)n * H + k] = hi;
        dlo[(size_t)n * H + k] = f2bf(v - bf2f(hi));
    }
}

// ---------- split-bf16 MFMA GEMM (big x@W): C = A[M][K] * B^T[N][K] ----------
template<int BM, int BN, int FM, int FN, bool AF32>
__global__ __launch_bounds__(256)
void gemm_mfma(const float* __restrict__ Af,
               const u16* __restrict__ Ahi, const u16* __restrict__ Alo, int lda,
               const u16* __restrict__ Bhi, const u16* __restrict__ Blo, int ldb,
               float* __restrict__ C, int ldc, int K)
{
    constexpr int NWN = BN / (FN * 16);
    constexpr int NWM = BM / (FM * 16);
    static_assert(NWM * NWN == 4, "need 4 waves");
    __shared__ char lds[(BM + BN) * 256];
    char* sAhi = lds;
    char* sAlo = lds + BM * 128;
    char* sBhi = lds + BM * 256;
    char* sBlo = lds + BM * 256 + BN * 128;

    const int tid = threadIdx.x;
    const int m0 = blockIdx.y * BM, n0 = blockIdx.x * BN;
    const int wid = tid >> 6, lane = tid & 63;
    const int wm = wid / NWN, wn = wid % NWN;
    const int lr = lane & 15, kg = lane >> 4;

    f32x4 acc[FM][FN] = {};

    for (int k0 = 0; k0 < K; k0 += 64) {
        if constexpr (AF32) {
            constexpr int NC = BM * 16 / 256;
            #pragma unroll
            for (int i = 0; i < NC; ++i) {
                int c = tid + i * 256;
                int row = c >> 4, kc = c & 15;
                const float4 v = *(const float4*)(Af + (size_t)(m0 + row) * lda + k0 + kc * 4);
                u16 h0 = f2bf(v.x), h1 = f2bf(v.y), h2 = f2bf(v.z), h3 = f2bf(v.w);
                u16 l0 = f2bf(v.x - bf2f(h0)), l1 = f2bf(v.y - bf2f(h1));
                u16 l2 = f2bf(v.z - bf2f(h2)), l3 = f2bf(v.w - bf2f(h3));
                uint2 hp, lp;
                hp.x = (u32)h0 | ((u32)h1 << 16); hp.y = (u32)h2 | ((u32)h3 << 16);
                lp.x = (u32)l0 | ((u32)l1 << 16); lp.y = (u32)l2 | ((u32)l3 << 16);
                int boff = row * 128 + ((((kc >> 1)) ^ (row & 7)) << 4) + ((kc & 1) << 3);
                *(uint2*)(sAhi + boff) = hp;
                *(uint2*)(sAlo + boff) = lp;
            }
        } else {
            constexpr int NC = BM * 8 / 256;
            #pragma unroll
            for (int i = 0; i < NC; ++i) {
                int c = tid + i * 256;
                int row = c >> 3, kc = c & 7;
                int boff = row * 128 + ((kc ^ (row & 7)) << 4);
                *(float4*)(sAhi + boff) = *(const float4*)(Ahi + (size_t)(m0 + row) * lda + k0 + kc * 8);
                *(float4*)(sAlo + boff) = *(const float4*)(Alo + (size_t)(m0 + row) * lda + k0 + kc * 8);
            }
        }
        {
            constexpr int NC = BN * 8 / 256;
            #pragma unroll
            for (int i = 0; i < NC; ++i) {
                int c = tid + i * 256;
                int row = c >> 3, kc = c & 7;
                int boff = row * 128 + ((kc ^ (row & 7)) << 4);
                *(float4*)(sBhi + boff) = *(const float4*)(Bhi + (size_t)(n0 + row) * ldb + k0 + kc * 8);
                *(float4*)(sBlo + boff) = *(const float4*)(Blo + (size_t)(n0 + row) * ldb + k0 + kc * 8);
            }
        }
        __syncthreads();

        #pragma unroll
        for (int ks = 0; ks < 2; ++ks) {
            short8 ah[FM], al[FM], bh[FN], bl[FN];
            #pragma unroll
            for (int mi = 0; mi < FM; ++mi) {
                int row = wm * FM * 16 + mi * 16 + lr;
                int off = row * 128 + ((((ks << 2) | kg) ^ (row & 7)) << 4);
                ah[mi] = *(const short8*)(sAhi + off);
                al[mi] = *(const short8*)(sAlo + off);
            }
            #pragma unroll
            for (int ni = 0; ni < FN; ++ni) {
                int row = wn * FN * 16 + ni * 16 + lr;
                int off = row * 128 + ((((ks << 2) | kg) ^ (row & 7)) << 4);
                bh[ni] = *(const short8*)(sBhi + off);
                bl[ni] = *(const short8*)(sBlo + off);
            }
            #pragma unroll
            for (int mi = 0; mi < FM; ++mi)
                #pragma unroll
                for (int ni = 0; ni < FN; ++ni) {
                    acc[mi][ni] = __builtin_amdgcn_mfma_f32_16x16x32_bf16(ah[mi], bh[ni], acc[mi][ni], 0, 0, 0);
                    acc[mi][ni] = __builtin_amdgcn_mfma_f32_16x16x32_bf16(ah[mi], bl[ni], acc[mi][ni], 0, 0, 0);
                    acc[mi][ni] = __builtin_amdgcn_mfma_f32_16x16x32_bf16(al[mi], bh[ni], acc[mi][ni], 0, 0, 0);
                }
        }
        __syncthreads();
    }

    #pragma unroll
    for (int mi = 0; mi < FM; ++mi)
        #pragma unroll
        for (int ni = 0; ni < FN; ++ni) {
            int col = n0 + wn * FN * 16 + ni * 16 + lr;
            #pragma unroll
            for (int r = 0; r < 4; ++r) {
                int row = m0 + wm * FM * 16 + mi * 16 + kg * 4 + r;
                C[(size_t)row * ldc + col] = acc[mi][ni][r];
            }
        }
}

// ---------- block reduce (sum, sumsq) over 256 threads ----------
__device__ inline void block_reduce2(float& s, float& sq, int tid) {
    #pragma unroll
    for (int off = 32; off > 0; off >>= 1) { s += __shfl_down(s, off); sq += __shfl_down(sq, off); }
    __shared__ float rs[4], rq[4];
    if ((tid & 63) == 0) { rs[tid >> 6] = s; rq[tid >> 6] = sq; }
    __syncthreads();
    s  = rs[0] + rs[1] + rs[2] + rs[3];
    sq = rq[0] + rq[1] + rq[2] + rq[3];
    __syncthreads();
}

// ---------- LN over S1 rows of 3072 (adds bias first), in place, gamma0/beta0 ----------
__global__ __launch_bounds__(256)
void ln_rows_v(float* __restrict__ S1, const float* __restrict__ bias,
               const float* __restrict__ gammas, const float* __restrict__ betas)
{
    const int row = blockIdx.x, tid = threadIdx.x;
    float* p = S1 + (size_t)row * INNER;
    float a[12];
    float s = 0.f, sq = 0.f;
    #pragma unroll
    for (int i = 0; i < 3; ++i) {
        int c = tid + i * 256;
        float4 v = *(const float4*)(p + c * 4);
        float4 bb = *(const float4*)(bias + c * 4);
        a[i*4+0] = v.x + bb.x; a[i*4+1] = v.y + bb.y; a[i*4+2] = v.z + bb.z; a[i*4+3] = v.w + bb.w;
        s += a[i*4+0] + a[i*4+1] + a[i*4+2] + a[i*4+3];
        sq += a[i*4+0]*a[i*4+0] + a[i*4+1]*a[i*4+1] + a[i*4+2]*a[i*4+2] + a[i*4+3]*a[i*4+3];
    }
    block_reduce2(s, sq, tid);
    const float mean = s / (float)INNER;
    const float var  = sq / (float)INNER - mean * mean;
    const float denom = sqrtf(var + EPSF) + EPSF;
    #pragma unroll
    for (int i = 0; i < 3; ++i) {
        int c = tid + i * 256;
        float4 o;
        o.x = gammas[c*4+0] * (a[i*4+0] - mean) / denom + betas[c*4+0];
        o.y = gammas[c*4+1] * (a[i*4+1] - mean) / denom + betas[c*4+1];
        o.z = gammas[c*4+2] * (a[i*4+2] - mean) / denom + betas[c*4+2];
        o.w = gammas[c*4+3] * (a[i*4+3] - mean) / denom + betas[c*4+3];
        *(float4*)(p + c * 4) = o;
    }
}

// ================= persistent-kernel phase bodies =================

template<int BM, int BN, int FM, int FN>
__device__ __forceinline__
void gemm_body(const u16* __restrict__ Ahi, const u16* __restrict__ Alo,
               const u16* __restrict__ Bhi, const u16* __restrict__ Blo,
               float* __restrict__ C, int ldc, int m0, int n0, char* lds)
{
    constexpr int NWN = BN / (FN * 16);
    char* sAhi = lds;
    char* sAlo = lds + BM * 128;
    char* sBhi = lds + BM * 256;
    char* sBlo = lds + BM * 256 + BN * 128;
    const int tid = threadIdx.x;
    const int wid = tid >> 6, lane = tid & 63;
    const int wm = wid / NWN, wn = wid % NWN;
    const int lr = lane & 15, kg = lane >> 4;
    f32x4 acc[FM][FN] = {};

    for (int k0 = 0; k0 < H; k0 += 64) {
        constexpr int NCA = BM * 8 / 256;
        #pragma unroll
        for (int i = 0; i < NCA; ++i) {
            int c = tid + i * 256;
            int row = c >> 3, kc = c & 7;
            int boff = row * 128 + ((kc ^ (row & 7)) << 4);
            *(float4*)(sAhi + boff) = *(const float4*)(Ahi + (size_t)(m0 + row) * H + k0 + kc * 8);
            *(float4*)(sAlo + boff) = *(const float4*)(Alo + (size_t)(m0 + row) * H + k0 + kc * 8);
        }
        constexpr int NCB = BN * 8 / 256;
        #pragma unroll
        for (int i = 0; i < NCB; ++i) {
            int c = tid + i * 256;
            int row = c >> 3, kc = c & 7;
            int boff = row * 128 + ((kc ^ (row & 7)) << 4);
            *(float4*)(sBhi + boff) = *(const float4*)(Bhi + (size_t)(n0 + row) * H + k0 + kc * 8);
            *(float4*)(sBlo + boff) = *(const float4*)(Blo + (size_t)(n0 + row) * H + k0 + kc * 8);
        }
        __syncthreads();

        #pragma unroll
        for (int ks = 0; ks < 2; ++ks) {
            short8 ah[FM], al[FM], bh[FN], bl[FN];
            #pragma unroll
            for (int mi = 0; mi < FM; ++mi) {
                int row = wm * FM * 16 + mi * 16 + lr;
                int off = row * 128 + ((((ks << 2) | kg) ^ (row & 7)) << 4);
                ah[mi] = *(const short8*)(sAhi + off);
                al[mi] = *(const short8*)(sAlo + off);
            }
            #pragma unroll
            for (int ni = 0; ni < FN; ++ni) {
                int row = wn * FN * 16 + ni * 16 + lr;
                int off = row * 128 + ((((ks << 2) | kg) ^ (row & 7)) << 4);
                bh[ni] = *(const short8*)(sBhi + off);
                bl[ni] = *(const short8*)(sBlo + off);
            }
            #pragma unroll
            for (int mi = 0; mi < FM; ++mi)
                #pragma unroll
                for (int ni = 0; ni < FN; ++ni) {
                    acc[mi][ni] = __builtin_amdgcn_mfma_f32_16x16x32_bf16(ah[mi], bh[ni], acc[mi][ni], 0, 0, 0);
                    acc[mi][ni] = __builtin_amdgcn_mfma_f32_16x16x32_bf16(ah[mi], bl[ni], acc[mi][ni], 0, 0, 0);
                    acc[mi][ni] = __builtin_amdgcn_mfma_f32_16x16x32_bf16(al[mi], bh[ni], acc[mi][ni], 0, 0, 0);
                }
        }
        __syncthreads();
    }

    #pragma unroll
    for (int mi = 0; mi < FM; ++mi)
        #pragma unroll
        for (int ni = 0; ni < FN; ++ni) {
            int col = n0 + wn * FN * 16 + ni * 16 + lr;
            #pragma unroll
            for (int r = 0; r < 4; ++r) {
                int row = m0 + wm * FM * 16 + mi * 16 + kg * 4 + r;
                C[(size_t)row * ldc + col] = acc[mi][ni][r];
            }
        }
}

__device__ __forceinline__
void e1_body(const float* __restrict__ s2raw, const float* __restrict__ S1,
             const float* __restrict__ h,
             const float* __restrict__ gammas, const float* __restrict__ betas,
             float* __restrict__ z, u16* __restrict__ rh_hi, u16* __restrict__ rh_lo,
             int t, int b)
{
    const int tid = threadIdx.x;
    const float* row = s2raw + (size_t)b * NZ;
    float az[4], ar[4];
    {
        float4 vz = *(const float4*)(row + tid * 4);
        float4 vr = *(const float4*)(row + 1024 + tid * 4);
        az[0]=vz.x; az[1]=vz.y; az[2]=vz.z; az[3]=vz.w;
        ar[0]=vr.x; ar[1]=vr.y; ar[2]=vr.z; ar[3]=vr.w;
    }
    float s = 0.f, sq = 0.f;
    #pragma unroll
    for (int q = 0; q < 4; ++q) { s += az[q] + ar[q]; sq += az[q]*az[q] + ar[q]*ar[q]; }
    block_reduce2(s, sq, tid);
    const float mean = s / (float)NZ;
    const float var  = sq / (float)NZ - mean * mean;
    const float denom = sqrtf(var + EPSF) + EPSF;

    const float* s1 = S1 + (size_t)(b * T + t) * INNER;
    const int j0 = tid * 4;
    float4 zo;
    float* zp = (float*)&zo;
    #pragma unroll
    for (int q = 0; q < 4; ++q) {
        int j = j0 + q;
        float ln = gammas[INNER + j] * (az[q] - mean) / denom + betas[INNER + j];
        float sv = 0.2f * (s1[j] + ln) + 0.5f;
        zp[q] = fminf(fmaxf(sv, 0.f), 1.f);
    }
    *(float4*)(z + (size_t)b * H + j0) = zo;

    uint2 hp, lp;
    u16 hh[4], ll[4];
    #pragma unroll
    for (int q = 0; q < 4; ++q) {
        int j = 1024 + j0 + q;
        float ln = gammas[INNER + j] * (ar[q] - mean) / denom + betas[INNER + j];
        float sv = 0.2f * (s1[j] + ln) + 0.5f;
        sv = fminf(fmaxf(sv, 0.f), 1.f);
        float rv = sv * h[(size_t)b * H + j0 + q];
        hh[q] = f2bf(rv);
        ll[q] = f2bf(rv - bf2f(hh[q]));
    }
    hp.x = (u32)hh[0] | ((u32)hh[1] << 16); hp.y = (u32)hh[2] | ((u32)hh[3] << 16);
    lp.x = (u32)ll[0] | ((u32)ll[1] << 16); lp.y = (u32)ll[2] | ((u32)ll[3] << 16);
    *(uint2*)(rh_hi + (size_t)b * H + j0) = hp;
    *(uint2*)(rh_lo + (size_t)b * H + j0) = lp;
}

__device__ __forceinline__
void e2_body(const float* __restrict__ candraw, const float* __restrict__ S1,
             const float* __restrict__ gammas, const float* __restrict__ betas,
             const float* __restrict__ z, float* __restrict__ h,
             u16* __restrict__ h_hi, u16* __restrict__ h_lo,
             float* __restrict__ out, int t, int b)
{
    const int tid = threadIdx.x;
    float a[4];
    {
        float4 v = *(const float4*)(candraw + (size_t)b * H + tid * 4);
        a[0]=v.x; a[1]=v.y; a[2]=v.z; a[3]=v.w;
    }
    float s = a[0]+a[1]+a[2]+a[3];
    float sq = a[0]*a[0]+a[1]*a[1]+a[2]*a[2]+a[3]*a[3];
    block_reduce2(s, sq, tid);
    const float mean = s / (float)H;
    const float var  = sq / (float)H - mean * mean;
    const float denom = sqrtf(var + EPSF) + EPSF;

    const float* s1 = S1 + (size_t)(b * T + t) * INNER + NZ;
    const int j0 = tid * 4;
    float4 ho, oo;
    float* hp_ = (float*)&ho; float* op = (float*)&oo;
    u16 hh[4], ll[4];
    #pragma unroll
    for (int q = 0; q < 4; ++q) {
        int j = j0 + q;
        float ln = gammas[INNER + NZ + j] * (a[q] - mean) / denom + betas[INNER + NZ + j];
        float cand = tanhf(s1[j] + ln);
        float zz = z[(size_t)b * H + j];
        float hold = h[(size_t)b * H + j];
        float hn = zz * hold + (1.f - zz) * cand;
        hp_[q] = hn; op[q] = hn;
        hh[q] = f2bf(hn);
        ll[q] = f2bf(hn - bf2f(hh[q]));
    }
    *(float4*)(h + (size_t)b * H + j0) = ho;
    uint2 hpck, lpck;
    hpck.x = (u32)hh[0] | ((u32)hh[1] << 16); hpck.y = (u32)hh[2] | ((u32)hh[3] << 16);
    lpck.x = (u32)ll[0] | ((u32)ll[1] << 16); lpck.y = (u32)ll[2] | ((u32)ll[3] << 16);
    *(uint2*)(h_hi + (size_t)b * H + j0) = hpck;
    *(uint2*)(h_lo + (size_t)b * H + j0) = lpck;
    *(float4*)(out + ((size_t)b * T + t) * H + j0) = oo;
}

// ================= the persistent cooperative step loop =================
__global__ __launch_bounds__(256)
void rnn_steps(const u16* __restrict__ UT_hi, const u16* __restrict__ UT_lo,
               const float* __restrict__ S1,
               const float* __restrict__ gammas, const float* __restrict__ betas,
               float* __restrict__ h, float* __restrict__ z,
               float* __restrict__ s2raw, float* __restrict__ candraw,
               u16* __restrict__ h_hi, u16* __restrict__ h_lo,
               u16* __restrict__ rh_hi, u16* __restrict__ rh_lo,
               float* __restrict__ out)
{
    cg::grid_group grid = cg::this_grid();
    __shared__ char lds[(32 + 64) * 256];
    const int blk = blockIdx.x;
    const u16* Uc_hi = UT_hi + (size_t)NZ * H;
    const u16* Uc_lo = UT_lo + (size_t)NZ * H;

    for (int t = 0; t < T; ++t) {
        // G1: s2raw = h_split @ Uzr^T   (32x64 tiles, 8x32 = 256 blocks)
        gemm_body<32, 64, 1, 2>(h_hi, h_lo, UT_hi, UT_lo, s2raw, NZ,
                                (blk >> 5) * 32, (blk & 31) * 64, lds);
        grid.sync();
        // e1: LN(s2) -> z, rh(split)
        e1_body(s2raw, S1, h, gammas, betas, z, rh_hi, rh_lo, t, blk);
        grid.sync();
        // G2: candraw = rh_split @ Uc^T  (32x32 tiles, 8x32 = 256 blocks)
        gemm_body<32, 32, 1, 1>(rh_hi, rh_lo, Uc_hi, Uc_lo, candraw, H,
                                (blk >> 5) * 32, (blk & 31) * 32, lds);
        grid.sync();
        // e2: LN(cand) -> tanh -> h update, out[t]
        e2_body(candraw, S1, gammas, betas, z, h, h_hi, h_lo, out, t, blk);
        if (t + 1 < T) grid.sync();
    }
}

// ================= fallback (validated fp32 path) =================
__global__ __launch_bounds__(256)
void gemm_fb(const float* __restrict__ A, int lda,
             const float* __restrict__ Bm, int ldb,
             float* __restrict__ C, int ldc, int K)
{
    constexpr int BM = 64, BN = 64, BK = 16;
    __shared__ float As[BK][BM];
    __shared__ float Bs[BK][BN];
    const int tid = threadIdx.x;
    const int tx = tid & 15, ty = tid >> 4;
    float acc[4][4] = {};
    const float* Ab = A + (size_t)blockIdx.y * BM * lda;
    const float* Bb = Bm + (size_t)blockIdx.x * BN;
    for (int k0 = 0; k0 < K; k0 += BK) {
        #pragma unroll
        for (int i = 0; i < 4; ++i) {
            int e = tid + i * 256; int m = e >> 4, k = e & 15;
            As[k][m] = Ab[(size_t)m * lda + k0 + k];
        }
        #pragma unroll
        for (int i = 0; i < 4; ++i) {
            int e = tid + i * 256; int k = e >> 6, n = e & 63;
            Bs[k][n] = Bb[(size_t)(k0 + k) * ldb + n];
        }
        __syncthreads();
        #pragma unroll
        for (int k = 0; k < BK; ++k) {
            float av[4], bv[4];
            #pragma unroll
            for (int i = 0; i < 4; ++i) av[i] = As[k][ty * 4 + i];
            #pragma unroll
            for (int j = 0; j < 4; ++j) bv[j] = Bs[k][tx * 4 + j];
            #pragma unroll
            for (int i = 0; i < 4; ++i)
                #pragma unroll
                for (int j = 0; j < 4; ++j)
                    acc[i][j] = fmaf(av[i], bv[j], acc[i][j]);
        }
        __syncthreads();
    }
    const int row0 = blockIdx.y * BM + ty * 4;
    const int col0 = blockIdx.x * BN + tx * 4;
    #pragma unroll
    for (int i = 0; i < 4; ++i)
        #pragma unroll
        for (int j = 0; j < 4; ++j)
            C[(size_t)(row0 + i) * ldc + col0 + j] = acc[i][j];
}

__global__ __launch_bounds__(256)
void step_e1_fb(const float* __restrict__ s2raw, const float* __restrict__ S1,
                const float* __restrict__ h,
                const float* __restrict__ gammas, const float* __restrict__ betas,
                float* __restrict__ z, float* __restrict__ rh, int t)
{
    const int b = blockIdx.x, tid = threadIdx.x;
    const float* row = s2raw + (size_t)b * NZ;
    float v[8]; float s = 0.f, sq = 0.f;
    #pragma unroll
    for (int i = 0; i < 8; ++i) { v[i] = row[tid + i * 256]; s += v[i]; sq += v[i]*v[i]; }
    block_reduce2(s, sq, tid);
    const float mean = s / (float)NZ;
    const float var  = sq / (float)NZ - mean * mean;
    const float denom = sqrtf(var + EPSF) + EPSF;
    const float* s1 = S1 + (size_t)(b * T + t) * INNER;
    #pragma unroll
    for (int i = 0; i < 8; ++i) {
        int j = tid + i * 256;
        float ln = gammas[INNER + j] * (v[i] - mean) / denom + betas[INNER + j];
        float sv = 0.2f * (s1[j] + ln) + 0.5f;
        sv = fminf(fmaxf(sv, 0.f), 1.f);
        if (j < H) z[(size_t)b * H + j] = sv;
        else       rh[(size_t)b * H + (j - H)] = sv * h[(size_t)b * H + (j - H)];
    }
}

__global__ __launch_bounds__(256)
void step_e2_fb(const float* __restrict__ candraw, const float* __restrict__ S1,
                const float* __restrict__ gammas, const float* __restrict__ betas,
                const float* __restrict__ z, float* __restrict__ h,
                float* __restrict__ out, int t)
{
    const int b = blockIdx.x, tid = threadIdx.x;
    float v[4]; float s = 0.f, sq = 0.f;
    #pragma unroll
    for (int i = 0; i < 4; ++i) { v[i] = candraw[(size_t)b * H + tid + i * 256]; s += v[i]; sq += v[i]*v[i]; }
    block_reduce2(s, sq, tid);
    const float mean = s / (float)H;
    const float var  = sq / (float)H - mean * mean;
    const float denom = sqrtf(var + EPSF) + EPSF;
    const float* s1 = S1 + (size_t)(b * T + t) * INNER + NZ;
    #pragma unroll
    for (int i = 0; i < 4; ++i) {
        int j = tid + i * 256;
        float ln = gammas[INNER + NZ + j] * (v[i] - mean) / denom + betas[INNER + NZ + j];
        float cand = tanhf(s1[j] + ln);
        float zz = z[(size_t)b * H + j];
        float hold = h[(size_t)b * H + j];
        float hn = zz * hold + (1.f - zz) * cand;
        h[(size_t)b * H + j] = hn;
        out[((size_t)b * T + t) * H + j] = hn;
    }
}

// ================= launch =================
extern "C" void kernel_launch(void* const* d_in, const int* in_sizes, int n_in,
                              void* d_out, int out_size, void* d_ws, size_t ws_size,
                              hipStream_t stream) {
    const float* x      = (const float*)d_in[0];
    const float* W      = (const float*)d_in[1];
    const float* U      = (const float*)d_in[2];
    const float* bias   = (const float*)d_in[3];
    const float* gammas = (const float*)d_in[4];
    const float* betas  = (const float*)d_in[5];
    float* out = (float*)d_out;
    (void)in_sizes; (void)n_in; (void)out_size;

    char* ws = (char*)d_ws;
    size_t off = 0;
    auto alloc = [&](size_t bytes) { void* p = ws + off; off += (bytes + 255) & ~(size_t)255; return p; };

    const size_t sz_S1 = (size_t)BT * INNER * 4;          // 402.7 MB
    const size_t sz_T  = (size_t)INNER * H * 2;           // 6.29 MB per split half
    const size_t need_new = sz_S1 + 4 * sz_T + ((size_t)B * H * 4) * 3 + (size_t)B * NZ * 4
                          + ((size_t)B * H * 2) * 4 + 16 * 1024;   // ~435 MB

    if (ws_size >= need_new) {
        float* S1    = (float*)alloc(sz_S1);
        u16* WT_hi   = (u16*)alloc(sz_T);
        u16* WT_lo   = (u16*)alloc(sz_T);
        u16* UT_hi   = (u16*)alloc(sz_T);
        u16* UT_lo   = (u16*)alloc(sz_T);
        float* h     = (float*)alloc((size_t)B * H * 4);
        float* z     = (float*)alloc((size_t)B * H * 4);
        float* s2raw = (float*)alloc((size_t)B * NZ * 4);
        float* candraw = (float*)alloc((size_t)B * H * 4);
        u16* h_hi    = (u16*)alloc((size_t)B * H * 2);
        u16* h_lo    = (u16*)alloc((size_t)B * H * 2);
        u16* rh_hi   = (u16*)alloc((size_t)B * H * 2);
        u16* rh_lo   = (u16*)alloc((size_t)B * H * 2);

        transpose_split<<<dim3(INNER / 32, H / 32), 256, 0, stream>>>(W, WT_hi, WT_lo);
        transpose_split<<<dim3(INNER / 32, H / 32), 256, 0, stream>>>(U, UT_hi, UT_lo);

        // S1raw = x @ W  (bias added in ln_rows_v)
        gemm_mfma<128, 128, 4, 4, true><<<dim3(INNER / 128, BT / 128), 256, 0, stream>>>(
            x, nullptr, nullptr, H, WT_hi, WT_lo, H, S1, INNER, H);
        ln_rows_v<<<BT, 256, 0, stream>>>(S1, bias, gammas, betas);

        hipMemsetAsync(h,    0, (size_t)B * H * 4, stream);
        hipMemsetAsync(h_hi, 0, (size_t)B * H * 2, stream);
        hipMemsetAsync(h_lo, 0, (size_t)B * H * 2, stream);

        const u16* UT_hi_c = UT_hi;
        const u16* UT_lo_c = UT_lo;
        const float* S1_c = S1;
        void* kargs[] = {
            (void*)&UT_hi_c, (void*)&UT_lo_c, (void*)&S1_c,
            (void*)&gammas, (void*)&betas,
            (void*)&h, (void*)&z, (void*)&s2raw, (void*)&candraw,
            (void*)&h_hi, (void*)&h_lo, (void*)&rh_hi, (void*)&rh_lo,
            (void*)&out
        };
        hipLaunchCooperativeKernel((void*)rnn_steps, dim3(256), dim3(256), kargs, 0, stream);
    } else {
        // fallback: validated fp32 path
        float* S1    = (float*)alloc(sz_S1);
        float* h     = (float*)alloc((size_t)B * H * 4);
        float* z     = (float*)alloc((size_t)B * H * 4);
        float* rh    = (float*)alloc((size_t)B * H * 4);
        float* s2raw = (float*)alloc((size_t)B * NZ * 4);
        float* candraw = (float*)alloc((size_t)B * H * 4);

        hipMemsetAsync(h, 0, (size_t)B * H * 4, stream);
        gemm_fb<<<dim3(INNER / 64, BT / 64), 256, 0, stream>>>(x, H, W, INNER, S1, INNER, H);
        ln_rows_v<<<BT, 256, 0, stream>>>(S1, bias, gammas, betas);
        for (int t = 0; t < T; ++t) {
            gemm_fb<<<dim3(NZ / 64, B / 64), 256, 0, stream>>>(h, H, U, INNER, s2raw, NZ, H);
            step_e1_fb<<<B, 256, 0, stream>>>(s2raw, S1, h, gammas, betas, z, rh, t);
            gemm_fb<<<dim3(H / 64, B / 64), 256, 0, stream>>>(rh, H, U + NZ, INNER, candraw, H, H);
            step_e2_fb<<<B, 256, 0, stream>>>(candraw, S1, gammas, betas, z, h, out, t);
        }
    }
}

// Round 7
// 8204.350 us; speedup vs baseline: 2.4216x; 2.4216x over previous
//
#include <hip/hip_runtime.h>
#include <hip/hip_bf16.h>

#define EPSF 1e-5f

typedef unsigned short u16;
typedef unsigned int   u32;
typedef __attribute__((ext_vector_type(8))) short short8;
typedef __attribute__((ext_vector_type(4))) float f32x4;

constexpr int B  = 256;
constexpr int T  = 128;
constexpr int H  = 1024;
constexpr int INNER = 3 * H;   // 3072
constexpr int BT = B * T;      // 32768
constexpr int NZ = 2 * H;      // 2048

__device__ inline u16 f2bf(float v) {
    u32 u = __float_as_uint(v);
    return (u16)((u + 0x7fffu + ((u >> 16) & 1u)) >> 16);
}
__device__ inline float bf2f(u16 h) { return __uint_as_float(((u32)h) << 16); }

// ---------- one-time: transpose fp32 [1024][3072] -> split bf16 [3072][1024] ----------
__global__ __launch_bounds__(256)
void transpose_split(const float* __restrict__ src, u16* __restrict__ dhi, u16* __restrict__ dlo)
{
    __shared__ float tile[32][33];
    const int tx = threadIdx.x & 31, ty = threadIdx.x >> 5;
    const int bx = blockIdx.x, by = blockIdx.y;
    #pragma unroll
    for (int i = 0; i < 4; ++i)
        tile[ty + i * 8][tx] = src[(size_t)(by * 32 + ty + i * 8) * INNER + bx * 32 + tx];
    __syncthreads();
    #pragma unroll
    for (int i = 0; i < 4; ++i) {
        int n = bx * 32 + ty + i * 8;
        int k = by * 32 + tx;
        float v = tile[tx][ty + i * 8];
        u16 hi = f2bf(v);
        dhi[(size_t)n * H + k] = hi;
        dlo[(size_t)n * H + k] = f2bf(v - bf2f(hi));
    }
}

// ---------- split-bf16 MFMA GEMM (big x@W): C = A[M][K] * B^T[N][K] ----------
template<int BM, int BN, int FM, int FN, bool AF32>
__global__ __launch_bounds__(256)
void gemm_mfma(const float* __restrict__ Af,
               const u16* __restrict__ Ahi, const u16* __restrict__ Alo, int lda,
               const u16* __restrict__ Bhi, const u16* __restrict__ Blo, int ldb,
               float* __restrict__ C, int ldc, int K)
{
    constexpr int NWN = BN / (FN * 16);
    constexpr int NWM = BM / (FM * 16);
    static_assert(NWM * NWN == 4, "need 4 waves");
    __shared__ char lds[(BM + BN) * 256];
    char* sAhi = lds;
    char* sAlo = lds + BM * 128;
    char* sBhi = lds + BM * 256;
    char* sBlo = lds + BM * 256 + BN * 128;

    const int tid = threadIdx.x;
    const int m0 = blockIdx.y * BM, n0 = blockIdx.x * BN;
    const int wid = tid >> 6, lane = tid & 63;
    const int wm = wid / NWN, wn = wid % NWN;
    const int lr = lane & 15, kg = lane >> 4;

    f32x4 acc[FM][FN] = {};

    for (int k0 = 0; k0 < K; k0 += 64) {
        if constexpr (AF32) {
            constexpr int NC = BM * 16 / 256;
            #pragma unroll
            for (int i = 0; i < NC; ++i) {
                int c = tid + i * 256;
                int row = c >> 4, kc = c & 15;
                const float4 v = *(const float4*)(Af + (size_t)(m0 + row) * lda + k0 + kc * 4);
                u16 h0 = f2bf(v.x), h1 = f2bf(v.y), h2 = f2bf(v.z), h3 = f2bf(v.w);
                u16 l0 = f2bf(v.x - bf2f(h0)), l1 = f2bf(v.y - bf2f(h1));
                u16 l2 = f2bf(v.z - bf2f(h2)), l3 = f2bf(v.w - bf2f(h3));
                uint2 hp, lp;
                hp.x = (u32)h0 | ((u32)h1 << 16); hp.y = (u32)h2 | ((u32)h3 << 16);
                lp.x = (u32)l0 | ((u32)l1 << 16); lp.y = (u32)l2 | ((u32)l3 << 16);
                int boff = row * 128 + ((((kc >> 1)) ^ (row & 7)) << 4) + ((kc & 1) << 3);
                *(uint2*)(sAhi + boff) = hp;
                *(uint2*)(sAlo + boff) = lp;
            }
        } else {
            constexpr int NC = BM * 8 / 256;
            #pragma unroll
            for (int i = 0; i < NC; ++i) {
                int c = tid + i * 256;
                int row = c >> 3, kc = c & 7;
                int boff = row * 128 + ((kc ^ (row & 7)) << 4);
                *(float4*)(sAhi + boff) = *(const float4*)(Ahi + (size_t)(m0 + row) * lda + k0 + kc * 8);
                *(float4*)(sAlo + boff) = *(const float4*)(Alo + (size_t)(m0 + row) * lda + k0 + kc * 8);
            }
        }
        {
            constexpr int NC = BN * 8 / 256;
            #pragma unroll
            for (int i = 0; i < NC; ++i) {
                int c = tid + i * 256;
                int row = c >> 3, kc = c & 7;
                int boff = row * 128 + ((kc ^ (row & 7)) << 4);
                *(float4*)(sBhi + boff) = *(const float4*)(Bhi + (size_t)(n0 + row) * ldb + k0 + kc * 8);
                *(float4*)(sBlo + boff) = *(const float4*)(Blo + (size_t)(n0 + row) * ldb + k0 + kc * 8);
            }
        }
        __syncthreads();

        #pragma unroll
        for (int ks = 0; ks < 2; ++ks) {
            short8 ah[FM], al[FM], bh[FN], bl[FN];
            #pragma unroll
            for (int mi = 0; mi < FM; ++mi) {
                int row = wm * FM * 16 + mi * 16 + lr;
                int off = row * 128 + ((((ks << 2) | kg) ^ (row & 7)) << 4);
                ah[mi] = *(const short8*)(sAhi + off);
                al[mi] = *(const short8*)(sAlo + off);
            }
            #pragma unroll
            for (int ni = 0; ni < FN; ++ni) {
                int row = wn * FN * 16 + ni * 16 + lr;
                int off = row * 128 + ((((ks << 2) | kg) ^ (row & 7)) << 4);
                bh[ni] = *(const short8*)(sBhi + off);
                bl[ni] = *(const short8*)(sBlo + off);
            }
            #pragma unroll
            for (int mi = 0; mi < FM; ++mi)
                #pragma unroll
                for (int ni = 0; ni < FN; ++ni) {
                    acc[mi][ni] = __builtin_amdgcn_mfma_f32_16x16x32_bf16(ah[mi], bh[ni], acc[mi][ni], 0, 0, 0);
                    acc[mi][ni] = __builtin_amdgcn_mfma_f32_16x16x32_bf16(ah[mi], bl[ni], acc[mi][ni], 0, 0, 0);
                    acc[mi][ni] = __builtin_amdgcn_mfma_f32_16x16x32_bf16(al[mi], bh[ni], acc[mi][ni], 0, 0, 0);
                }
        }
        __syncthreads();
    }

    #pragma unroll
    for (int mi = 0; mi < FM; ++mi)
        #pragma unroll
        for (int ni = 0; ni < FN; ++ni) {
            int col = n0 + wn * FN * 16 + ni * 16 + lr;
            #pragma unroll
            for (int r = 0; r < 4; ++r) {
                int row = m0 + wm * FM * 16 + mi * 16 + kg * 4 + r;
                C[(size_t)row * ldc + col] = acc[mi][ni][r];
            }
        }
}

// ---------- block reduce (sum, sumsq) over 256 threads ----------
__device__ inline void block_reduce2(float& s, float& sq, int tid) {
    #pragma unroll
    for (int off = 32; off > 0; off >>= 1) { s += __shfl_down(s, off); sq += __shfl_down(sq, off); }
    __shared__ float rs[4], rq[4];
    if ((tid & 63) == 0) { rs[tid >> 6] = s; rq[tid >> 6] = sq; }
    __syncthreads();
    s  = rs[0] + rs[1] + rs[2] + rs[3];
    sq = rq[0] + rq[1] + rq[2] + rq[3];
    __syncthreads();
}

// ---------- LN over S1 rows of 3072 (adds bias first), in place ----------
__global__ __launch_bounds__(256)
void ln_rows_v(float* __restrict__ S1, const float* __restrict__ bias,
               const float* __restrict__ gammas, const float* __restrict__ betas)
{
    const int row = blockIdx.x, tid = threadIdx.x;
    float* p = S1 + (size_t)row * INNER;
    float a[12];
    float s = 0.f, sq = 0.f;
    #pragma unroll
    for (int i = 0; i < 3; ++i) {
        int c = tid + i * 256;
        float4 v = *(const float4*)(p + c * 4);
        float4 bb = *(const float4*)(bias + c * 4);
        a[i*4+0] = v.x + bb.x; a[i*4+1] = v.y + bb.y; a[i*4+2] = v.z + bb.z; a[i*4+3] = v.w + bb.w;
        s += a[i*4+0] + a[i*4+1] + a[i*4+2] + a[i*4+3];
        sq += a[i*4+0]*a[i*4+0] + a[i*4+1]*a[i*4+1] + a[i*4+2]*a[i*4+2] + a[i*4+3]*a[i*4+3];
    }
    block_reduce2(s, sq, tid);
    const float mean = s / (float)INNER;
    const float var  = sq / (float)INNER - mean * mean;
    const float denom = sqrtf(var + EPSF) + EPSF;
    #pragma unroll
    for (int i = 0; i < 3; ++i) {
        int c = tid + i * 256;
        float4 o;
        o.x = gammas[c*4+0] * (a[i*4+0] - mean) / denom + betas[c*4+0];
        o.y = gammas[c*4+1] * (a[i*4+1] - mean) / denom + betas[c*4+1];
        o.z = gammas[c*4+2] * (a[i*4+2] - mean) / denom + betas[c*4+2];
        o.w = gammas[c*4+3] * (a[i*4+3] - mean) / denom + betas[c*4+3];
        *(float4*)(p + c * 4) = o;
    }
}

// ================= stepK1: G1 (h_split @ Uzr^T -> s2raw) + partial row stats =================
// 256 blocks (XCD-swizzled: 8m x 32n of 32x64 tiles), 256 threads.
__global__ __launch_bounds__(256)
void stepK1(const u16* __restrict__ h_hi, const u16* __restrict__ h_lo,
            const u16* __restrict__ Bhi, const u16* __restrict__ Blo,
            float* __restrict__ s2raw, float* __restrict__ s2part)
{
    constexpr int BM = 32, BN = 64;
    __shared__ char lds[(BM + BN) * 256];
    char* sAhi = lds;
    char* sAlo = lds + BM * 128;
    char* sBhi = lds + BM * 256;
    char* sBlo = lds + BM * 256 + BN * 128;

    const int tid = threadIdx.x;
    const int blk = blockIdx.x;
    // XCD swizzle: blk%8 picks XCD; XCD x owns n-tiles [4x, 4x+4) -> Uzr slice ~1MB L2-resident
    const int x = blk & 7, inr = blk >> 3;
    const int m0 = (inr >> 2) * BM;
    const int nt = x * 4 + (inr & 3);
    const int n0 = nt * BN;

    const int wid = tid >> 6, lane = tid & 63;
    const int wm = wid >> 1, wn = wid & 1;
    const int lr = lane & 15, kg = lane >> 4;

    f32x4 acc[2] = {};   // FM=1, FN=2

    for (int k0 = 0; k0 < H; k0 += 64) {
        {   // A: 32 rows x 64k (1 iter)
            int row = tid >> 3, kc = tid & 7;
            int boff = row * 128 + ((kc ^ (row & 7)) << 4);
            *(float4*)(sAhi + boff) = *(const float4*)(h_hi + (size_t)(m0 + row) * H + k0 + kc * 8);
            *(float4*)(sAlo + boff) = *(const float4*)(h_lo + (size_t)(m0 + row) * H + k0 + kc * 8);
        }
        #pragma unroll
        for (int i = 0; i < 2; ++i) {  // B: 64 rows
            int c = tid + i * 256;
            int row = c >> 3, kc = c & 7;
            int boff = row * 128 + ((kc ^ (row & 7)) << 4);
            *(float4*)(sBhi + boff) = *(const float4*)(Bhi + (size_t)(n0 + row) * H + k0 + kc * 8);
            *(float4*)(sBlo + boff) = *(const float4*)(Blo + (size_t)(n0 + row) * H + k0 + kc * 8);
        }
        __syncthreads();

        #pragma unroll
        for (int ks = 0; ks < 2; ++ks) {
            short8 ah, al, bh[2], bl[2];
            {
                int row = wm * 16 + lr;
                int off = row * 128 + ((((ks << 2) | kg) ^ (row & 7)) << 4);
                ah = *(const short8*)(sAhi + off);
                al = *(const short8*)(sAlo + off);
            }
            #pragma unroll
            for (int ni = 0; ni < 2; ++ni) {
                int row = wn * 32 + ni * 16 + lr;
                int off = row * 128 + ((((ks << 2) | kg) ^ (row & 7)) << 4);
                bh[ni] = *(const short8*)(sBhi + off);
                bl[ni] = *(const short8*)(sBlo + off);
            }
            #pragma unroll
            for (int ni = 0; ni < 2; ++ni) {
                acc[ni] = __builtin_amdgcn_mfma_f32_16x16x32_bf16(ah, bh[ni], acc[ni], 0, 0, 0);
                acc[ni] = __builtin_amdgcn_mfma_f32_16x16x32_bf16(ah, bl[ni], acc[ni], 0, 0, 0);
                acc[ni] = __builtin_amdgcn_mfma_f32_16x16x32_bf16(al, bh[ni], acc[ni], 0, 0, 0);
            }
        }
        __syncthreads();
    }

    #pragma unroll
    for (int ni = 0; ni < 2; ++ni) {
        int col = n0 + wn * 32 + ni * 16 + lr;
        #pragma unroll
        for (int r = 0; r < 4; ++r) {
            int row = m0 + wm * 16 + kg * 4 + r;
            s2raw[(size_t)row * NZ + col] = acc[ni][r];
        }
    }
    // deterministic partial stats: this wave's 32 cols per row; slot = nt*2 + wn (64 slots)
    const int slot = nt * 2 + wn;
    #pragma unroll
    for (int r = 0; r < 4; ++r) {
        float v0 = acc[0][r], v1 = acc[1][r];
        float s = v0 + v1, q = v0 * v0 + v1 * v1;
        s += __shfl_xor(s, 1); q += __shfl_xor(q, 1);
        s += __shfl_xor(s, 2); q += __shfl_xor(q, 2);
        s += __shfl_xor(s, 4); q += __shfl_xor(q, 4);
        s += __shfl_xor(s, 8); q += __shfl_xor(q, 8);
        if (lr == 0) {
            int row = m0 + wm * 16 + kg * 4 + r;
            s2part[((size_t)slot * B + row) * 2 + 0] = s;
            s2part[((size_t)slot * B + row) * 2 + 1] = q;
        }
    }
}

// ================= stepK2: fused rh-staging + G2 (rh @ Uc^T -> candraw) + cand partials =================
// 256 blocks (XCD-swizzled: 16m x 16n of 16x64 tiles), 256 threads.
__global__ __launch_bounds__(256)
void stepK2(const float* __restrict__ s2raw, const float* __restrict__ s2part,
            const float* __restrict__ h, const float* __restrict__ S1,
            const float* __restrict__ gammas, const float* __restrict__ betas,
            const u16* __restrict__ Bhi, const u16* __restrict__ Blo,
            float* __restrict__ candraw, float* __restrict__ candpart, int t)
{
    constexpr int BM = 16, BN = 64;
    __shared__ char lds[(BM + BN) * 256];
    __shared__ float stats[BM][2];
    char* sAhi = lds;
    char* sAlo = lds + BM * 128;
    char* sBhi = lds + BM * 256;
    char* sBlo = lds + BM * 256 + BN * 128;

    const int tid = threadIdx.x;
    const int blk = blockIdx.x;
    const int x = blk & 7, inr = blk >> 3;
    const int m0 = (inr >> 1) * BM;
    const int nt = x * 2 + (inr & 1);
    const int n0 = nt * BN;

    // per-row LN stats over full 2048 row from 64 deterministic partials
    {
        const int row = tid >> 4, j = tid & 15;
        float s = 0.f, q = 0.f;
        #pragma unroll
        for (int i = 0; i < 4; ++i) {
            int sl = j * 4 + i;
            s += s2part[((size_t)sl * B + m0 + row) * 2 + 0];
            q += s2part[((size_t)sl * B + m0 + row) * 2 + 1];
        }
        s += __shfl_xor(s, 1); q += __shfl_xor(q, 1);
        s += __shfl_xor(s, 2); q += __shfl_xor(q, 2);
        s += __shfl_xor(s, 4); q += __shfl_xor(q, 4);
        s += __shfl_xor(s, 8); q += __shfl_xor(q, 8);
        if (j == 0) {
            float mean = s / (float)NZ;
            float var  = q / (float)NZ - mean * mean;
            stats[row][0] = mean;
            stats[row][1] = 1.f / (sqrtf(var + EPSF) + EPSF);
        }
    }
    __syncthreads();

    const int wid = tid >> 6, lane = tid & 63;
    const int wn = wid;                   // NWM=1, NWN=4
    const int lr = lane & 15, kg = lane >> 4;
    f32x4 acc = {};

    for (int k0 = 0; k0 < H; k0 += 64) {
        {   // fused A-staging: rh = clip(0.2*(s1 + LN(s2_r)) + 0.5) * h, split to bf16 hi/lo
            int row = tid >> 4, kc = tid & 15;
            int b = m0 + row, k = k0 + kc * 4;
            float4 sv  = *(const float4*)(s2raw + (size_t)b * NZ + 1024 + k);
            float4 hv  = *(const float4*)(h + (size_t)b * H + k);
            float4 s1v = *(const float4*)(S1 + ((size_t)b * T + t) * INNER + 1024 + k);
            float4 gv  = *(const float4*)(gammas + INNER + 1024 + k);
            float4 bv  = *(const float4*)(betas  + INNER + 1024 + k);
            const float mean = stats[row][0], rden = stats[row][1];
            float r0 = fminf(fmaxf(0.2f * (s1v.x + gv.x * (sv.x - mean) * rden + bv.x) + 0.5f, 0.f), 1.f) * hv.x;
            float r1 = fminf(fmaxf(0.2f * (s1v.y + gv.y * (sv.y - mean) * rden + bv.y) + 0.5f, 0.f), 1.f) * hv.y;
            float r2 = fminf(fmaxf(0.2f * (s1v.z + gv.z * (sv.z - mean) * rden + bv.z) + 0.5f, 0.f), 1.f) * hv.z;
            float r3 = fminf(fmaxf(0.2f * (s1v.w + gv.w * (sv.w - mean) * rden + bv.w) + 0.5f, 0.f), 1.f) * hv.w;
            u16 h0 = f2bf(r0), h1 = f2bf(r1), h2 = f2bf(r2), h3 = f2bf(r3);
            u16 l0 = f2bf(r0 - bf2f(h0)), l1 = f2bf(r1 - bf2f(h1));
            u16 l2 = f2bf(r2 - bf2f(h2)), l3 = f2bf(r3 - bf2f(h3));
            uint2 hp, lp;
            hp.x = (u32)h0 | ((u32)h1 << 16); hp.y = (u32)h2 | ((u32)h3 << 16);
            lp.x = (u32)l0 | ((u32)l1 << 16); lp.y = (u32)l2 | ((u32)l3 << 16);
            int boff = row * 128 + ((((kc >> 1)) ^ (row & 7)) << 4) + ((kc & 1) << 3);
            *(uint2*)(sAhi + boff) = hp;
            *(uint2*)(sAlo + boff) = lp;
        }
        #pragma unroll
        for (int i = 0; i < 2; ++i) {  // B: 64 rows of Uc
            int c = tid + i * 256;
            int row = c >> 3, kc = c & 7;
            int boff = row * 128 + ((kc ^ (row & 7)) << 4);
            *(float4*)(sBhi + boff) = *(const float4*)(Bhi + (size_t)(n0 + row) * H + k0 + kc * 8);
            *(float4*)(sBlo + boff) = *(const float4*)(Blo + (size_t)(n0 + row) * H + k0 + kc * 8);
        }
        __syncthreads();

        #pragma unroll
        for (int ks = 0; ks < 2; ++ks) {
            short8 ah, al, bh, bl;
            {
                int row = lr;
                int off = row * 128 + ((((ks << 2) | kg) ^ (row & 7)) << 4);
                ah = *(const short8*)(sAhi + off);
                al = *(const short8*)(sAlo + off);
            }
            {
                int row = wn * 16 + lr;
                int off = row * 128 + ((((ks << 2) | kg) ^ (row & 7)) << 4);
                bh = *(const short8*)(sBhi + off);
                bl = *(const short8*)(sBlo + off);
            }
            acc = __builtin_amdgcn_mfma_f32_16x16x32_bf16(ah, bh, acc, 0, 0, 0);
            acc = __builtin_amdgcn_mfma_f32_16x16x32_bf16(ah, bl, acc, 0, 0, 0);
            acc = __builtin_amdgcn_mfma_f32_16x16x32_bf16(al, bh, acc, 0, 0, 0);
        }
        __syncthreads();
    }

    {
        int col = n0 + wn * 16 + lr;
        #pragma unroll
        for (int r = 0; r < 4; ++r) {
            int row = m0 + kg * 4 + r;
            candraw[(size_t)row * H + col] = acc[r];
        }
    }
    // cand partial stats: slot = nt*4 + wn (64 slots of 16 cols)
    const int slot = nt * 4 + wn;
    #pragma unroll
    for (int r = 0; r < 4; ++r) {
        float s = acc[r], q = acc[r] * acc[r];
        s += __shfl_xor(s, 1); q += __shfl_xor(q, 1);
        s += __shfl_xor(s, 2); q += __shfl_xor(q, 2);
        s += __shfl_xor(s, 4); q += __shfl_xor(q, 4);
        s += __shfl_xor(s, 8); q += __shfl_xor(q, 8);
        if (lr == 0) {
            int row = m0 + kg * 4 + r;
            candpart[((size_t)slot * B + row) * 2 + 0] = s;
            candpart[((size_t)slot * B + row) * 2 + 1] = q;
        }
    }
}

// ================= stepK3: z + cand LN + tanh + h update + out[t] =================
__global__ __launch_bounds__(256)
void stepK3(const float* __restrict__ s2raw, const float* __restrict__ s2part,
            const float* __restrict__ candraw, const float* __restrict__ candpart,
            const float* __restrict__ S1,
            const float* __restrict__ gammas, const float* __restrict__ betas,
            float* __restrict__ h, u16* __restrict__ h_hi, u16* __restrict__ h_lo,
            float* __restrict__ out, int t)
{
    const int b = blockIdx.x, tid = threadIdx.x;
    __shared__ float st[4];   // mean2, rden2, meanc, rdenc
    if (tid < 64) {
        float s = s2part[((size_t)tid * B + b) * 2 + 0];
        float q = s2part[((size_t)tid * B + b) * 2 + 1];
        #pragma unroll
        for (int m = 1; m < 64; m <<= 1) { s += __shfl_xor(s, m); q += __shfl_xor(q, m); }
        if (tid == 0) {
            float mean = s / (float)NZ;
            float var  = q / (float)NZ - mean * mean;
            st[0] = mean; st[1] = 1.f / (sqrtf(var + EPSF) + EPSF);
        }
    } else if (tid < 128) {
        int l = tid - 64;
        float s = candpart[((size_t)l * B + b) * 2 + 0];
        float q = candpart[((size_t)l * B + b) * 2 + 1];
        #pragma unroll
        for (int m = 1; m < 64; m <<= 1) { s += __shfl_xor(s, m); q += __shfl_xor(q, m); }
        if (l == 0) {
            float mean = s / (float)H;
            float var  = q / (float)H - mean * mean;
            st[2] = mean; st[3] = 1.f / (sqrtf(var + EPSF) + EPSF);
        }
    }
    __syncthreads();
    const float mean2 = st[0], rden2 = st[1], meanc = st[2], rdenc = st[3];

    const int j0 = tid * 4;
    const float* s1base = S1 + ((size_t)b * T + t) * INNER;
    float4 s2v = *(const float4*)(s2raw + (size_t)b * NZ + j0);
    float4 s1z = *(const float4*)(s1base + j0);
    float4 gz  = *(const float4*)(gammas + INNER + j0);
    float4 bz  = *(const float4*)(betas  + INNER + j0);
    float4 cv  = *(const float4*)(candraw + (size_t)b * H + j0);
    float4 s1c = *(const float4*)(s1base + NZ + j0);
    float4 gc  = *(const float4*)(gammas + INNER + NZ + j0);
    float4 bc  = *(const float4*)(betas  + INNER + NZ + j0);
    float4 hv  = *(const float4*)(h + (size_t)b * H + j0);

    float zq[4], cq[4], hq[4];
    const float* s2p = (const float*)&s2v; const float* z1 = (const float*)&s1z;
    const float* gp = (const float*)&gz;  const float* bp = (const float*)&bz;
    const float* cp = (const float*)&cv;  const float* c1 = (const float*)&s1c;
    const float* gcp = (const float*)&gc; const float* bcp = (const float*)&bc;
    const float* hp = (const float*)&hv;
    #pragma unroll
    for (int q = 0; q < 4; ++q) {
        float zv = 0.2f * (z1[q] + gp[q] * (s2p[q] - mean2) * rden2 + bp[q]) + 0.5f;
        zv = fminf(fmaxf(zv, 0.f), 1.f);
        float cand = tanhf(c1[q] + gcp[q] * (cp[q] - meanc) * rdenc + bcp[q]);
        float hn = zv * hp[q] + (1.f - zv) * cand;
        zq[q] = zv; cq[q] = cand; hq[q] = hn;
    }
    float4 ho; float* hop = (float*)&ho;
    hop[0]=hq[0]; hop[1]=hq[1]; hop[2]=hq[2]; hop[3]=hq[3];
    *(float4*)(h + (size_t)b * H + j0) = ho;
    *(float4*)(out + ((size_t)b * T + t) * H + j0) = ho;
    u16 hh[4], ll[4];
    #pragma unroll
    for (int q = 0; q < 4; ++q) {
        hh[q] = f2bf(hq[q]);
        ll[q] = f2bf(hq[q] - bf2f(hh[q]));
    }
    uint2 hpck, lpck;
    hpck.x = (u32)hh[0] | ((u32)hh[1] << 16); hpck.y = (u32)hh[2] | ((u32)hh[3] << 16);
    lpck.x = (u32)ll[0] | ((u32)ll[1] << 16); lpck.y = (u32)ll[2] | ((u32)ll[3] << 16);
    *(uint2*)(h_hi + (size_t)b * H + j0) = hpck;
    *(uint2*)(h_lo + (size_t)b * H + j0) = lpck;
}

// ================= fallback (validated fp32 path) =================
__global__ __launch_bounds__(256)
void gemm_fb(const float* __restrict__ A, int lda,
             const float* __restrict__ Bm, int ldb,
             float* __restrict__ C, int ldc, int K)
{
    constexpr int BM = 64, BN = 64, BK = 16;
    __shared__ float As[BK][BM];
    __shared__ float Bs[BK][BN];
    const int tid = threadIdx.x;
    const int tx = tid & 15, ty = tid >> 4;
    float acc[4][4] = {};
    const float* Ab = A + (size_t)blockIdx.y * BM * lda;
    const float* Bb = Bm + (size_t)blockIdx.x * BN;
    for (int k0 = 0; k0 < K; k0 += BK) {
        #pragma unroll
        for (int i = 0; i < 4; ++i) {
            int e = tid + i * 256; int m = e >> 4, k = e & 15;
            As[k][m] = Ab[(size_t)m * lda + k0 + k];
        }
        #pragma unroll
        for (int i = 0; i < 4; ++i) {
            int e = tid + i * 256; int k = e >> 6, n = e & 63;
            Bs[k][n] = Bb[(size_t)(k0 + k) * ldb + n];
        }
        __syncthreads();
        #pragma unroll
        for (int k = 0; k < BK; ++k) {
            float av[4], bv[4];
            #pragma unroll
            for (int i = 0; i < 4; ++i) av[i] = As[k][ty * 4 + i];
            #pragma unroll
            for (int j = 0; j < 4; ++j) bv[j] = Bs[k][tx * 4 + j];
            #pragma unroll
            for (int i = 0; i < 4; ++i)
                #pragma unroll
                for (int j = 0; j < 4; ++j)
                    acc[i][j] = fmaf(av[i], bv[j], acc[i][j]);
        }
        __syncthreads();
    }
    const int row0 = blockIdx.y * BM + ty * 4;
    const int col0 = blockIdx.x * BN + tx * 4;
    #pragma unroll
    for (int i = 0; i < 4; ++i)
        #pragma unroll
        for (int j = 0; j < 4; ++j)
            C[(size_t)(row0 + i) * ldc + col0 + j] = acc[i][j];
}

__global__ __launch_bounds__(256)
void step_e1_fb(const float* __restrict__ s2raw, const float* __restrict__ S1,
                const float* __restrict__ h,
                const float* __restrict__ gammas, const float* __restrict__ betas,
                float* __restrict__ z, float* __restrict__ rh, int t)
{
    const int b = blockIdx.x, tid = threadIdx.x;
    const float* row = s2raw + (size_t)b * NZ;
    float v[8]; float s = 0.f, sq = 0.f;
    #pragma unroll
    for (int i = 0; i < 8; ++i) { v[i] = row[tid + i * 256]; s += v[i]; sq += v[i]*v[i]; }
    block_reduce2(s, sq, tid);
    const float mean = s / (float)NZ;
    const float var  = sq / (float)NZ - mean * mean;
    const float denom = sqrtf(var + EPSF) + EPSF;
    const float* s1 = S1 + (size_t)(b * T + t) * INNER;
    #pragma unroll
    for (int i = 0; i < 8; ++i) {
        int j = tid + i * 256;
        float ln = gammas[INNER + j] * (v[i] - mean) / denom + betas[INNER + j];
        float sv = 0.2f * (s1[j] + ln) + 0.5f;
        sv = fminf(fmaxf(sv, 0.f), 1.f);
        if (j < H) z[(size_t)b * H + j] = sv;
        else       rh[(size_t)b * H + (j - H)] = sv * h[(size_t)b * H + (j - H)];
    }
}

__global__ __launch_bounds__(256)
void step_e2_fb(const float* __restrict__ candraw, const float* __restrict__ S1,
                const float* __restrict__ gammas, const float* __restrict__ betas,
                const float* __restrict__ z, float* __restrict__ h,
                float* __restrict__ out, int t)
{
    const int b = blockIdx.x, tid = threadIdx.x;
    float v[4]; float s = 0.f, sq = 0.f;
    #pragma unroll
    for (int i = 0; i < 4; ++i) { v[i] = candraw[(size_t)b * H + tid + i * 256]; s += v[i]; sq += v[i]*v[i]; }
    block_reduce2(s, sq, tid);
    const float mean = s / (float)H;
    const float var  = sq / (float)H - mean * mean;
    const float denom = sqrtf(var + EPSF) + EPSF;
    const float* s1 = S1 + (size_t)(b * T + t) * INNER + NZ;
    #pragma unroll
    for (int i = 0; i < 4; ++i) {
        int j = tid + i * 256;
        float ln = gammas[INNER + NZ + j] * (v[i] - mean) / denom + betas[INNER + NZ + j];
        float cand = tanhf(s1[j] + ln);
        float zz = z[(size_t)b * H + j];
        float hold = h[(size_t)b * H + j];
        float hn = zz * hold + (1.f - zz) * cand;
        h[(size_t)b * H + j] = hn;
        out[((size_t)b * T + t) * H + j] = hn;
    }
}

// ================= launch =================
extern "C" void kernel_launch(void* const* d_in, const int* in_sizes, int n_in,
                              void* d_out, int out_size, void* d_ws, size_t ws_size,
                              hipStream_t stream) {
    const float* x      = (const float*)d_in[0];
    const float* W      = (const float*)d_in[1];
    const float* U      = (const float*)d_in[2];
    const float* bias   = (const float*)d_in[3];
    const float* gammas = (const float*)d_in[4];
    const float* betas  = (const float*)d_in[5];
    float* out = (float*)d_out;
    (void)in_sizes; (void)n_in; (void)out_size;

    char* ws = (char*)d_ws;
    size_t off = 0;
    auto alloc = [&](size_t bytes) { void* p = ws + off; off += (bytes + 255) & ~(size_t)255; return p; };

    const size_t sz_S1 = (size_t)BT * INNER * 4;          // 402.7 MB
    const size_t sz_T  = (size_t)INNER * H * 2;           // 6.29 MB per split half
    const size_t sz_BH = (size_t)B * H * 4;               // 1 MB
    const size_t sz_part = (size_t)64 * B * 2 * 4;        // 128 KB
    const size_t need_new = sz_S1 + 4 * sz_T + sz_BH /*h*/ + (size_t)B * NZ * 4 /*s2raw*/
                          + sz_BH /*candraw*/ + ((size_t)B * H * 2) * 2 /*h splits*/
                          + 2 * sz_part + 16 * 1024;

    if (ws_size >= need_new) {
        float* S1     = (float*)alloc(sz_S1);
        u16* WT_hi    = (u16*)alloc(sz_T);
        u16* WT_lo    = (u16*)alloc(sz_T);
        u16* UT_hi    = (u16*)alloc(sz_T);
        u16* UT_lo    = (u16*)alloc(sz_T);
        float* h      = (float*)alloc(sz_BH);
        float* s2raw  = (float*)alloc((size_t)B * NZ * 4);
        float* candraw= (float*)alloc(sz_BH);
        u16* h_hi     = (u16*)alloc((size_t)B * H * 2);
        u16* h_lo     = (u16*)alloc((size_t)B * H * 2);
        float* s2part   = (float*)alloc(sz_part);
        float* candpart = (float*)alloc(sz_part);

        transpose_split<<<dim3(INNER / 32, H / 32), 256, 0, stream>>>(W, WT_hi, WT_lo);
        transpose_split<<<dim3(INNER / 32, H / 32), 256, 0, stream>>>(U, UT_hi, UT_lo);

        gemm_mfma<128, 128, 4, 4, true><<<dim3(INNER / 128, BT / 128), 256, 0, stream>>>(
            x, nullptr, nullptr, H, WT_hi, WT_lo, H, S1, INNER, H);
        ln_rows_v<<<BT, 256, 0, stream>>>(S1, bias, gammas, betas);

        hipMemsetAsync(h,    0, sz_BH, stream);
        hipMemsetAsync(h_hi, 0, (size_t)B * H * 2, stream);
        hipMemsetAsync(h_lo, 0, (size_t)B * H * 2, stream);

        const u16* Uc_hi = UT_hi + (size_t)NZ * H;
        const u16* Uc_lo = UT_lo + (size_t)NZ * H;

        for (int t = 0; t < T; ++t) {
            stepK1<<<256, 256, 0, stream>>>(h_hi, h_lo, UT_hi, UT_lo, s2raw, s2part);
            stepK2<<<256, 256, 0, stream>>>(s2raw, s2part, h, S1, gammas, betas,
                                            Uc_hi, Uc_lo, candraw, candpart, t);
            stepK3<<<256, 256, 0, stream>>>(s2raw, s2part, candraw, candpart, S1,
                                            gammas, betas, h, h_hi, h_lo, out, t);
        }
    } else {
        // fallback: validated fp32 path
        float* S1     = (float*)alloc(sz_S1);
        float* h      = (float*)alloc(sz_BH);
        float* z      = (float*)alloc(sz_BH);
        float* rh     = (float*)alloc(sz_BH);
        float* s2raw  = (float*)alloc((size_t)B * NZ * 4);
        float* candraw= (float*)alloc(sz_BH);

        hipMemsetAsync(h, 0, sz_BH, stream);
        gemm_fb<<<dim3(INNER / 64, BT / 64), 256, 0, stream>>>(x, H, W, INNER, S1, INNER, H);
        ln_rows_v<<<BT, 256, 0, stream>>>(S1, bias, gammas, betas);
        for (int t = 0; t < T; ++t) {
            gemm_fb<<<dim3(NZ / 64, B / 64), 256, 0, stream>>>(h, H, U, INNER, s2raw, NZ, H);
            step_e1_fb<<<B, 256, 0, stream>>>(s2raw, S1, h, gammas, betas, z, rh, t);
            gemm_fb<<<dim3(H / 64, B / 64), 256, 0, stream>>>(rh, H, U + NZ, INNER, candraw, H, H);
            step_e2_fb<<<B, 256, 0, stream>>>(candraw, S1, gammas, betas, z, h, out, t);
        }
    }
}

// Round 8
// 6787.870 us; speedup vs baseline: 2.9269x; 1.2087x over previous
//
#include <hip/hip_runtime.h>
#include <hip/hip_bf16.h>

#define EPSF 1e-5f

typedef unsigned short u16;
typedef unsigned int   u32;
typedef __attribute__((ext_vector_type(8))) short short8;
typedef __attribute__((ext_vector_type(4))) float f32x4;

constexpr int B  = 256;
constexpr int T  = 128;
constexpr int H  = 1024;
constexpr int INNER = 3 * H;   // 3072
constexpr int BT = B * T;      // 32768
constexpr int NZ = 2 * H;      // 2048

__device__ inline u16 f2bf(float v) {
    u32 u = __float_as_uint(v);
    return (u16)((u + 0x7fffu + ((u >> 16) & 1u)) >> 16);
}
__device__ inline float bf2f(u16 h) { return __uint_as_float(((u32)h) << 16); }

// ---------- one-time: transpose fp32 [1024][3072] -> split bf16 [3072][1024] ----------
__global__ __launch_bounds__(256)
void transpose_split(const float* __restrict__ src, u16* __restrict__ dhi, u16* __restrict__ dlo)
{
    __shared__ float tile[32][33];
    const int tx = threadIdx.x & 31, ty = threadIdx.x >> 5;
    const int bx = blockIdx.x, by = blockIdx.y;
    #pragma unroll
    for (int i = 0; i < 4; ++i)
        tile[ty + i * 8][tx] = src[(size_t)(by * 32 + ty + i * 8) * INNER + bx * 32 + tx];
    __syncthreads();
    #pragma unroll
    for (int i = 0; i < 4; ++i) {
        int n = bx * 32 + ty + i * 8;
        int k = by * 32 + tx;
        float v = tile[tx][ty + i * 8];
        u16 hi = f2bf(v);
        dhi[(size_t)n * H + k] = hi;
        dlo[(size_t)n * H + k] = f2bf(v - bf2f(hi));
    }
}

// ---------- split-bf16 MFMA GEMM (big x@W): C = A[M][K] * B^T[N][K] ----------
template<int BM, int BN, int FM, int FN, bool AF32>
__global__ __launch_bounds__(256)
void gemm_mfma(const float* __restrict__ Af,
               const u16* __restrict__ Ahi, const u16* __restrict__ Alo, int lda,
               const u16* __restrict__ Bhi, const u16* __restrict__ Blo, int ldb,
               float* __restrict__ C, int ldc, int K)
{
    constexpr int NWN = BN / (FN * 16);
    constexpr int NWM = BM / (FM * 16);
    static_assert(NWM * NWN == 4, "need 4 waves");
    __shared__ char lds[(BM + BN) * 256];
    char* sAhi = lds;
    char* sAlo = lds + BM * 128;
    char* sBhi = lds + BM * 256;
    char* sBlo = lds + BM * 256 + BN * 128;

    const int tid = threadIdx.x;
    const int m0 = blockIdx.y * BM, n0 = blockIdx.x * BN;
    const int wid = tid >> 6, lane = tid & 63;
    const int wm = wid / NWN, wn = wid % NWN;
    const int lr = lane & 15, kg = lane >> 4;

    f32x4 acc[FM][FN] = {};

    for (int k0 = 0; k0 < K; k0 += 64) {
        if constexpr (AF32) {
            constexpr int NC = BM * 16 / 256;
            #pragma unroll
            for (int i = 0; i < NC; ++i) {
                int c = tid + i * 256;
                int row = c >> 4, kc = c & 15;
                const float4 v = *(const float4*)(Af + (size_t)(m0 + row) * lda + k0 + kc * 4);
                u16 h0 = f2bf(v.x), h1 = f2bf(v.y), h2 = f2bf(v.z), h3 = f2bf(v.w);
                u16 l0 = f2bf(v.x - bf2f(h0)), l1 = f2bf(v.y - bf2f(h1));
                u16 l2 = f2bf(v.z - bf2f(h2)), l3 = f2bf(v.w - bf2f(h3));
                uint2 hp, lp;
                hp.x = (u32)h0 | ((u32)h1 << 16); hp.y = (u32)h2 | ((u32)h3 << 16);
                lp.x = (u32)l0 | ((u32)l1 << 16); lp.y = (u32)l2 | ((u32)l3 << 16);
                int boff = row * 128 + ((((kc >> 1)) ^ (row & 7)) << 4) + ((kc & 1) << 3);
                *(uint2*)(sAhi + boff) = hp;
                *(uint2*)(sAlo + boff) = lp;
            }
        } else {
            constexpr int NC = BM * 8 / 256;
            #pragma unroll
            for (int i = 0; i < NC; ++i) {
                int c = tid + i * 256;
                int row = c >> 3, kc = c & 7;
                int boff = row * 128 + ((kc ^ (row & 7)) << 4);
                *(float4*)(sAhi + boff) = *(const float4*)(Ahi + (size_t)(m0 + row) * lda + k0 + kc * 8);
                *(float4*)(sAlo + boff) = *(const float4*)(Alo + (size_t)(m0 + row) * lda + k0 + kc * 8);
            }
        }
        {
            constexpr int NC = BN * 8 / 256;
            #pragma unroll
            for (int i = 0; i < NC; ++i) {
                int c = tid + i * 256;
                int row = c >> 3, kc = c & 7;
                int boff = row * 128 + ((kc ^ (row & 7)) << 4);
                *(float4*)(sBhi + boff) = *(const float4*)(Bhi + (size_t)(n0 + row) * ldb + k0 + kc * 8);
                *(float4*)(sBlo + boff) = *(const float4*)(Blo + (size_t)(n0 + row) * ldb + k0 + kc * 8);
            }
        }
        __syncthreads();

        #pragma unroll
        for (int ks = 0; ks < 2; ++ks) {
            short8 ah[FM], al[FM], bh[FN], bl[FN];
            #pragma unroll
            for (int mi = 0; mi < FM; ++mi) {
                int row = wm * FM * 16 + mi * 16 + lr;
                int off = row * 128 + ((((ks << 2) | kg) ^ (row & 7)) << 4);
                ah[mi] = *(const short8*)(sAhi + off);
                al[mi] = *(const short8*)(sAlo + off);
            }
            #pragma unroll
            for (int ni = 0; ni < FN; ++ni) {
                int row = wn * FN * 16 + ni * 16 + lr;
                int off = row * 128 + ((((ks << 2) | kg) ^ (row & 7)) << 4);
                bh[ni] = *(const short8*)(sBhi + off);
                bl[ni] = *(const short8*)(sBlo + off);
            }
            #pragma unroll
            for (int mi = 0; mi < FM; ++mi)
                #pragma unroll
                for (int ni = 0; ni < FN; ++ni) {
                    acc[mi][ni] = __builtin_amdgcn_mfma_f32_16x16x32_bf16(ah[mi], bh[ni], acc[mi][ni], 0, 0, 0);
                    acc[mi][ni] = __builtin_amdgcn_mfma_f32_16x16x32_bf16(ah[mi], bl[ni], acc[mi][ni], 0, 0, 0);
                    acc[mi][ni] = __builtin_amdgcn_mfma_f32_16x16x32_bf16(al[mi], bh[ni], acc[mi][ni], 0, 0, 0);
                }
        }
        __syncthreads();
    }

    #pragma unroll
    for (int mi = 0; mi < FM; ++mi)
        #pragma unroll
        for (int ni = 0; ni < FN; ++ni) {
            int col = n0 + wn * FN * 16 + ni * 16 + lr;
            #pragma unroll
            for (int r = 0; r < 4; ++r) {
                int row = m0 + wm * FM * 16 + mi * 16 + kg * 4 + r;
                C[(size_t)row * ldc + col] = acc[mi][ni][r];
            }
        }
}

// ---------- pipelined small step-GEMM: pre-split A/B, XCD-swizzled n-tiles ----------
// grid = 256 blocks 1D. XCD x (= blk%8) owns n-tiles [x*NTPX, (x+1)*NTPX).
template<int BM, int BN, int FM, int FN, int NTPX>
__global__ __launch_bounds__(256)
void step_gemm(const u16* __restrict__ Ahi, const u16* __restrict__ Alo,
               const u16* __restrict__ Bhi, const u16* __restrict__ Blo,
               float* __restrict__ C, int ldc)
{
    constexpr int NWN = BN / (FN * 16);
    constexpr int NWM = BM / (FM * 16);
    static_assert(NWM * NWN == 4, "need 4 waves");
    constexpr int NCA = BM * 8 / 256;
    constexpr int NCB = BN * 8 / 256;
    __shared__ char lds[(BM + BN) * 256];
    char* sAhi = lds;
    char* sAlo = lds + BM * 128;
    char* sBhi = lds + BM * 256;
    char* sBlo = lds + BM * 256 + BN * 128;

    const int tid = threadIdx.x;
    const int blk = blockIdx.x;
    const int x = blk & 7, inr = blk >> 3;
    const int m0 = (inr / NTPX) * BM;
    const int n0 = (x * NTPX + (inr % NTPX)) * BN;

    const int wid = tid >> 6, lane = tid & 63;
    const int wm = wid / NWN, wn = wid % NWN;
    const int lr = lane & 15, kg = lane >> 4;

    f32x4 acc[FM][FN] = {};

    // register prefetch buffers
    float4 pa_hi[NCA], pa_lo[NCA], pb_hi[NCB], pb_lo[NCB];
    auto loadA = [&](int k0) {
        #pragma unroll
        for (int i = 0; i < NCA; ++i) {
            int c = tid + i * 256;
            int row = c >> 3, kc = c & 7;
            pa_hi[i] = *(const float4*)(Ahi + (size_t)(m0 + row) * H + k0 + kc * 8);
            pa_lo[i] = *(const float4*)(Alo + (size_t)(m0 + row) * H + k0 + kc * 8);
        }
    };
    auto loadB = [&](int k0) {
        #pragma unroll
        for (int i = 0; i < NCB; ++i) {
            int c = tid + i * 256;
            int row = c >> 3, kc = c & 7;
            pb_hi[i] = *(const float4*)(Bhi + (size_t)(n0 + row) * H + k0 + kc * 8);
            pb_lo[i] = *(const float4*)(Blo + (size_t)(n0 + row) * H + k0 + kc * 8);
        }
    };

    loadA(0); loadB(0);

    for (int k0 = 0; k0 < H; k0 += 64) {
        // commit prefetched regs to LDS
        #pragma unroll
        for (int i = 0; i < NCA; ++i) {
            int c = tid + i * 256;
            int row = c >> 3, kc = c & 7;
            int boff = row * 128 + ((kc ^ (row & 7)) << 4);
            *(float4*)(sAhi + boff) = pa_hi[i];
            *(float4*)(sAlo + boff) = pa_lo[i];
        }
        #pragma unroll
        for (int i = 0; i < NCB; ++i) {
            int c = tid + i * 256;
            int row = c >> 3, kc = c & 7;
            int boff = row * 128 + ((kc ^ (row & 7)) << 4);
            *(float4*)(sBhi + boff) = pb_hi[i];
            *(float4*)(sBlo + boff) = pb_lo[i];
        }
        __syncthreads();

        // issue next-tile loads; they fly while MFMA runs below
        if (k0 + 64 < H) { loadA(k0 + 64); loadB(k0 + 64); }

        #pragma unroll
        for (int ks = 0; ks < 2; ++ks) {
            short8 ah[FM], al[FM], bh[FN], bl[FN];
            #pragma unroll
            for (int mi = 0; mi < FM; ++mi) {
                int row = wm * FM * 16 + mi * 16 + lr;
                int off = row * 128 + ((((ks << 2) | kg) ^ (row & 7)) << 4);
                ah[mi] = *(const short8*)(sAhi + off);
                al[mi] = *(const short8*)(sAlo + off);
            }
            #pragma unroll
            for (int ni = 0; ni < FN; ++ni) {
                int row = wn * FN * 16 + ni * 16 + lr;
                int off = row * 128 + ((((ks << 2) | kg) ^ (row & 7)) << 4);
                bh[ni] = *(const short8*)(sBhi + off);
                bl[ni] = *(const short8*)(sBlo + off);
            }
            #pragma unroll
            for (int mi = 0; mi < FM; ++mi)
                #pragma unroll
                for (int ni = 0; ni < FN; ++ni) {
                    acc[mi][ni] = __builtin_amdgcn_mfma_f32_16x16x32_bf16(ah[mi], bh[ni], acc[mi][ni], 0, 0, 0);
                    acc[mi][ni] = __builtin_amdgcn_mfma_f32_16x16x32_bf16(ah[mi], bl[ni], acc[mi][ni], 0, 0, 0);
                    acc[mi][ni] = __builtin_amdgcn_mfma_f32_16x16x32_bf16(al[mi], bh[ni], acc[mi][ni], 0, 0, 0);
                }
        }
        __syncthreads();
    }

    #pragma unroll
    for (int mi = 0; mi < FM; ++mi)
        #pragma unroll
        for (int ni = 0; ni < FN; ++ni) {
            int col = n0 + wn * FN * 16 + ni * 16 + lr;
            #pragma unroll
            for (int r = 0; r < 4; ++r) {
                int row = m0 + wm * FM * 16 + mi * 16 + kg * 4 + r;
                C[(size_t)row * ldc + col] = acc[mi][ni][r];
            }
        }
}

// ---------- block reduce (sum, sumsq) over 256 threads ----------
__device__ inline void block_reduce2(float& s, float& sq, int tid) {
    #pragma unroll
    for (int off = 32; off > 0; off >>= 1) { s += __shfl_down(s, off); sq += __shfl_down(sq, off); }
    __shared__ float rs[4], rq[4];
    if ((tid & 63) == 0) { rs[tid >> 6] = s; rq[tid >> 6] = sq; }
    __syncthreads();
    s  = rs[0] + rs[1] + rs[2] + rs[3];
    sq = rq[0] + rq[1] + rq[2] + rq[3];
    __syncthreads();
}

// ---------- LN over S1 rows of 3072 (adds bias first), in place ----------
__global__ __launch_bounds__(256)
void ln_rows_v(float* __restrict__ S1, const float* __restrict__ bias,
               const float* __restrict__ gammas, const float* __restrict__ betas)
{
    const int row = blockIdx.x, tid = threadIdx.x;
    float* p = S1 + (size_t)row * INNER;
    float a[12];
    float s = 0.f, sq = 0.f;
    #pragma unroll
    for (int i = 0; i < 3; ++i) {
        int c = tid + i * 256;
        float4 v = *(const float4*)(p + c * 4);
        float4 bb = *(const float4*)(bias + c * 4);
        a[i*4+0] = v.x + bb.x; a[i*4+1] = v.y + bb.y; a[i*4+2] = v.z + bb.z; a[i*4+3] = v.w + bb.w;
        s += a[i*4+0] + a[i*4+1] + a[i*4+2] + a[i*4+3];
        sq += a[i*4+0]*a[i*4+0] + a[i*4+1]*a[i*4+1] + a[i*4+2]*a[i*4+2] + a[i*4+3]*a[i*4+3];
    }
    block_reduce2(s, sq, tid);
    const float mean = s / (float)INNER;
    const float var  = sq / (float)INNER - mean * mean;
    const float denom = sqrtf(var + EPSF) + EPSF;
    #pragma unroll
    for (int i = 0; i < 3; ++i) {
        int c = tid + i * 256;
        float4 o;
        o.x = gammas[c*4+0] * (a[i*4+0] - mean) / denom + betas[c*4+0];
        o.y = gammas[c*4+1] * (a[i*4+1] - mean) / denom + betas[c*4+1];
        o.z = gammas[c*4+2] * (a[i*4+2] - mean) / denom + betas[c*4+2];
        o.w = gammas[c*4+3] * (a[i*4+3] - mean) / denom + betas[c*4+3];
        *(float4*)(p + c * 4) = o;
    }
}

// ---------- step elementwise 1: LN(s2raw, 2048) -> z fp32, rh split bf16 ----------
__global__ __launch_bounds__(256)
void step_e1_v(const float* __restrict__ s2raw, const float* __restrict__ S1,
               const float* __restrict__ h,
               const float* __restrict__ gammas, const float* __restrict__ betas,
               float* __restrict__ z, u16* __restrict__ rh_hi, u16* __restrict__ rh_lo, int t)
{
    const int b = blockIdx.x, tid = threadIdx.x;
    const float* row = s2raw + (size_t)b * NZ;
    float az[4], ar[4];
    {
        float4 vz = *(const float4*)(row + tid * 4);
        float4 vr = *(const float4*)(row + 1024 + tid * 4);
        az[0]=vz.x; az[1]=vz.y; az[2]=vz.z; az[3]=vz.w;
        ar[0]=vr.x; ar[1]=vr.y; ar[2]=vr.z; ar[3]=vr.w;
    }
    float s = 0.f, sq = 0.f;
    #pragma unroll
    for (int q = 0; q < 4; ++q) { s += az[q] + ar[q]; sq += az[q]*az[q] + ar[q]*ar[q]; }
    block_reduce2(s, sq, tid);
    const float mean = s / (float)NZ;
    const float var  = sq / (float)NZ - mean * mean;
    const float denom = sqrtf(var + EPSF) + EPSF;

    const float* s1 = S1 + (size_t)(b * T + t) * INNER;
    const int j0 = tid * 4;
    float4 zo;
    float* zp = (float*)&zo;
    #pragma unroll
    for (int q = 0; q < 4; ++q) {
        int j = j0 + q;
        float ln = gammas[INNER + j] * (az[q] - mean) / denom + betas[INNER + j];
        float sv = 0.2f * (s1[j] + ln) + 0.5f;
        zp[q] = fminf(fmaxf(sv, 0.f), 1.f);
    }
    *(float4*)(z + (size_t)b * H + j0) = zo;

    uint2 hp, lp;
    u16 hh[4], ll[4];
    #pragma unroll
    for (int q = 0; q < 4; ++q) {
        int j = 1024 + j0 + q;
        float ln = gammas[INNER + j] * (ar[q] - mean) / denom + betas[INNER + j];
        float sv = 0.2f * (s1[j] + ln) + 0.5f;
        sv = fminf(fmaxf(sv, 0.f), 1.f);
        float rv = sv * h[(size_t)b * H + j0 + q];
        hh[q] = f2bf(rv);
        ll[q] = f2bf(rv - bf2f(hh[q]));
    }
    hp.x = (u32)hh[0] | ((u32)hh[1] << 16); hp.y = (u32)hh[2] | ((u32)hh[3] << 16);
    lp.x = (u32)ll[0] | ((u32)ll[1] << 16); lp.y = (u32)ll[2] | ((u32)ll[3] << 16);
    *(uint2*)(rh_hi + (size_t)b * H + j0) = hp;
    *(uint2*)(rh_lo + (size_t)b * H + j0) = lp;
}

// ---------- step elementwise 2: LN(candraw, 1024) -> tanh -> h update ----------
__global__ __launch_bounds__(256)
void step_e2_v(const float* __restrict__ candraw, const float* __restrict__ S1,
               const float* __restrict__ gammas, const float* __restrict__ betas,
               const float* __restrict__ z, float* __restrict__ h,
               u16* __restrict__ h_hi, u16* __restrict__ h_lo,
               float* __restrict__ out, int t)
{
    const int b = blockIdx.x, tid = threadIdx.x;
    float a[4];
    {
        float4 v = *(const float4*)(candraw + (size_t)b * H + tid * 4);
        a[0]=v.x; a[1]=v.y; a[2]=v.z; a[3]=v.w;
    }
    float s = a[0]+a[1]+a[2]+a[3];
    float sq = a[0]*a[0]+a[1]*a[1]+a[2]*a[2]+a[3]*a[3];
    block_reduce2(s, sq, tid);
    const float mean = s / (float)H;
    const float var  = sq / (float)H - mean * mean;
    const float denom = sqrtf(var + EPSF) + EPSF;

    const float* s1 = S1 + (size_t)(b * T + t) * INNER + NZ;
    const int j0 = tid * 4;
    float4 ho, oo;
    float* hp_ = (float*)&ho; float* op = (float*)&oo;
    u16 hh[4], ll[4];
    #pragma unroll
    for (int q = 0; q < 4; ++q) {
        int j = j0 + q;
        float ln = gammas[INNER + NZ + j] * (a[q] - mean) / denom + betas[INNER + NZ + j];
        float cand = tanhf(s1[j] + ln);
        float zz = z[(size_t)b * H + j];
        float hold = h[(size_t)b * H + j];
        float hn = zz * hold + (1.f - zz) * cand;
        hp_[q] = hn; op[q] = hn;
        hh[q] = f2bf(hn);
        ll[q] = f2bf(hn - bf2f(hh[q]));
    }
    *(float4*)(h + (size_t)b * H + j0) = ho;
    uint2 hpck, lpck;
    hpck.x = (u32)hh[0] | ((u32)hh[1] << 16); hpck.y = (u32)hh[2] | ((u32)hh[3] << 16);
    lpck.x = (u32)ll[0] | ((u32)ll[1] << 16); lpck.y = (u32)ll[2] | ((u32)ll[3] << 16);
    *(uint2*)(h_hi + (size_t)b * H + j0) = hpck;
    *(uint2*)(h_lo + (size_t)b * H + j0) = lpck;
    *(float4*)(out + ((size_t)b * T + t) * H + j0) = oo;
}

// ================= fallback (validated fp32 path) =================
__global__ __launch_bounds__(256)
void gemm_fb(const float* __restrict__ A, int lda,
             const float* __restrict__ Bm, int ldb,
             float* __restrict__ C, int ldc, int K)
{
    constexpr int BM = 64, BN = 64, BK = 16;
    __shared__ float As[BK][BM];
    __shared__ float Bs[BK][BN];
    const int tid = threadIdx.x;
    const int tx = tid & 15, ty = tid >> 4;
    float acc[4][4] = {};
    const float* Ab = A + (size_t)blockIdx.y * BM * lda;
    const float* Bb = Bm + (size_t)blockIdx.x * BN;
    for (int k0 = 0; k0 < K; k0 += BK) {
        #pragma unroll
        for (int i = 0; i < 4; ++i) {
            int e = tid + i * 256; int m = e >> 4, k = e & 15;
            As[k][m] = Ab[(size_t)m * lda + k0 + k];
        }
        #pragma unroll
        for (int i = 0; i < 4; ++i) {
            int e = tid + i * 256; int k = e >> 6, n = e & 63;
            Bs[k][n] = Bb[(size_t)(k0 + k) * ldb + n];
        }
        __syncthreads();
        #pragma unroll
        for (int k = 0; k < BK; ++k) {
            float av[4], bv[4];
            #pragma unroll
            for (int i = 0; i < 4; ++i) av[i] = As[k][ty * 4 + i];
            #pragma unroll
            for (int j = 0; j < 4; ++j) bv[j] = Bs[k][tx * 4 + j];
            #pragma unroll
            for (int i = 0; i < 4; ++i)
                #pragma unroll
                for (int j = 0; j < 4; ++j)
                    acc[i][j] = fmaf(av[i], bv[j], acc[i][j]);
        }
        __syncthreads();
    }
    const int row0 = blockIdx.y * BM + ty * 4;
    const int col0 = blockIdx.x * BN + tx * 4;
    #pragma unroll
    for (int i = 0; i < 4; ++i)
        #pragma unroll
        for (int j = 0; j < 4; ++j)
            C[(size_t)(row0 + i) * ldc + col0 + j] = acc[i][j];
}

__global__ __launch_bounds__(256)
void step_e1_fb(const float* __restrict__ s2raw, const float* __restrict__ S1,
                const float* __restrict__ h,
                const float* __restrict__ gammas, const float* __restrict__ betas,
                float* __restrict__ z, float* __restrict__ rh, int t)
{
    const int b = blockIdx.x, tid = threadIdx.x;
    const float* row = s2raw + (size_t)b * NZ;
    float v[8]; float s = 0.f, sq = 0.f;
    #pragma unroll
    for (int i = 0; i < 8; ++i) { v[i] = row[tid + i * 256]; s += v[i]; sq += v[i]*v[i]; }
    block_reduce2(s, sq, tid);
    const float mean = s / (float)NZ;
    const float var  = sq / (float)NZ - mean * mean;
    const float denom = sqrtf(var + EPSF) + EPSF;
    const float* s1 = S1 + (size_t)(b * T + t) * INNER;
    #pragma unroll
    for (int i = 0; i < 8; ++i) {
        int j = tid + i * 256;
        float ln = gammas[INNER + j] * (v[i] - mean) / denom + betas[INNER + j];
        float sv = 0.2f * (s1[j] + ln) + 0.5f;
        sv = fminf(fmaxf(sv, 0.f), 1.f);
        if (j < H) z[(size_t)b * H + j] = sv;
        else       rh[(size_t)b * H + (j - H)] = sv * h[(size_t)b * H + (j - H)];
    }
}

__global__ __launch_bounds__(256)
void step_e2_fb(const float* __restrict__ candraw, const float* __restrict__ S1,
                const float* __restrict__ gammas, const float* __restrict__ betas,
                const float* __restrict__ z, float* __restrict__ h,
                float* __restrict__ out, int t)
{
    const int b = blockIdx.x, tid = threadIdx.x;
    float v[4]; float s = 0.f, sq = 0.f;
    #pragma unroll
    for (int i = 0; i < 4; ++i) { v[i] = candraw[(size_t)b * H + tid + i * 256]; s += v[i]; sq += v[i]*v[i]; }
    block_reduce2(s, sq, tid);
    const float mean = s / (float)H;
    const float var  = sq / (float)H - mean * mean;
    const float denom = sqrtf(var + EPSF) + EPSF;
    const float* s1 = S1 + (size_t)(b * T + t) * INNER + NZ;
    #pragma unroll
    for (int i = 0; i < 4; ++i) {
        int j = tid + i * 256;
        float ln = gammas[INNER + NZ + j] * (v[i] - mean) / denom + betas[INNER + NZ + j];
        float cand = tanhf(s1[j] + ln);
        float zz = z[(size_t)b * H + j];
        float hold = h[(size_t)b * H + j];
        float hn = zz * hold + (1.f - zz) * cand;
        h[(size_t)b * H + j] = hn;
        out[((size_t)b * T + t) * H + j] = hn;
    }
}

// ================= launch =================
extern "C" void kernel_launch(void* const* d_in, const int* in_sizes, int n_in,
                              void* d_out, int out_size, void* d_ws, size_t ws_size,
                              hipStream_t stream) {
    const float* x      = (const float*)d_in[0];
    const float* W      = (const float*)d_in[1];
    const float* U      = (const float*)d_in[2];
    const float* bias   = (const float*)d_in[3];
    const float* gammas = (const float*)d_in[4];
    const float* betas  = (const float*)d_in[5];
    float* out = (float*)d_out;
    (void)in_sizes; (void)n_in; (void)out_size;

    char* ws = (char*)d_ws;
    size_t off = 0;
    auto alloc = [&](size_t bytes) { void* p = ws + off; off += (bytes + 255) & ~(size_t)255; return p; };

    const size_t sz_S1 = (size_t)BT * INNER * 4;          // 402.7 MB
    const size_t sz_T  = (size_t)INNER * H * 2;           // 6.29 MB per split half
    const size_t need_new = sz_S1 + 4 * sz_T + ((size_t)B * H * 4) * 3 + (size_t)B * NZ * 4
                          + ((size_t)B * H * 2) * 4 + 16 * 1024;   // ~435 MB

    if (ws_size >= need_new) {
        float* S1    = (float*)alloc(sz_S1);
        u16* WT_hi   = (u16*)alloc(sz_T);
        u16* WT_lo   = (u16*)alloc(sz_T);
        u16* UT_hi   = (u16*)alloc(sz_T);
        u16* UT_lo   = (u16*)alloc(sz_T);
        float* h     = (float*)alloc((size_t)B * H * 4);
        float* z     = (float*)alloc((size_t)B * H * 4);
        float* s2raw = (float*)alloc((size_t)B * NZ * 4);
        float* candraw = (float*)alloc((size_t)B * H * 4);
        u16* h_hi    = (u16*)alloc((size_t)B * H * 2);
        u16* h_lo    = (u16*)alloc((size_t)B * H * 2);
        u16* rh_hi   = (u16*)alloc((size_t)B * H * 2);
        u16* rh_lo   = (u16*)alloc((size_t)B * H * 2);

        transpose_split<<<dim3(INNER / 32, H / 32), 256, 0, stream>>>(W, WT_hi, WT_lo);
        transpose_split<<<dim3(INNER / 32, H / 32), 256, 0, stream>>>(U, UT_hi, UT_lo);

        gemm_mfma<128, 128, 4, 4, true><<<dim3(INNER / 128, BT / 128), 256, 0, stream>>>(
            x, nullptr, nullptr, H, WT_hi, WT_lo, H, S1, INNER, H);
        ln_rows_v<<<BT, 256, 0, stream>>>(S1, bias, gammas, betas);

        hipMemsetAsync(h,    0, (size_t)B * H * 4, stream);
        hipMemsetAsync(h_hi, 0, (size_t)B * H * 2, stream);
        hipMemsetAsync(h_lo, 0, (size_t)B * H * 2, stream);

        const u16* Uc_hi = UT_hi + (size_t)NZ * H;
        const u16* Uc_lo = UT_lo + (size_t)NZ * H;

        for (int t = 0; t < T; ++t) {
            // G1: s2raw = h @ Uzr^T  (32x64 tiles, 8m x 32n, XCD-swizzled: 4 n-tiles/XCD)
            step_gemm<32, 64, 1, 2, 4><<<256, 256, 0, stream>>>(
                h_hi, h_lo, UT_hi, UT_lo, s2raw, NZ);
            step_e1_v<<<B, 256, 0, stream>>>(s2raw, S1, h, gammas, betas, z, rh_hi, rh_lo, t);
            // G2: candraw = rh @ Uc^T (32x32 tiles, 8m x 32n, XCD-swizzled)
            step_gemm<32, 32, 1, 1, 4><<<256, 256, 0, stream>>>(
                rh_hi, rh_lo, Uc_hi, Uc_lo, candraw, H);
            step_e2_v<<<B, 256, 0, stream>>>(candraw, S1, gammas, betas, z, h, h_hi, h_lo, out, t);
        }
    } else {
        // fallback: validated fp32 path
        float* S1    = (float*)alloc(sz_S1);
        float* h     = (float*)alloc((size_t)B * H * 4);
        float* z     = (float*)alloc((size_t)B * H * 4);
        float* rh    = (float*)alloc((size_t)B * H * 4);
        float* s2raw = (float*)alloc((size_t)B * NZ * 4);
        float* candraw = (float*)alloc((size_t)B * H * 4);

        hipMemsetAsync(h, 0, (size_t)B * H * 4, stream);
        gemm_fb<<<dim3(INNER / 64, BT / 64), 256, 0, stream>>>(x, H, W, INNER, S1, INNER, H);
        ln_rows_v<<<BT, 256, 0, stream>>>(S1, bias, gammas, betas);
        for (int t = 0; t < T; ++t) {
            gemm_fb<<<dim3(NZ / 64, B / 64), 256, 0, stream>>>(h, H, U, INNER, s2raw, NZ, H);
            step_e1_fb<<<B, 256, 0, stream>>>(s2raw, S1, h, gammas, betas, z, rh, t);
            gemm_fb<<<dim3(H / 64, B / 64), 256, 0, stream>>>(rh, H, U + NZ, INNER, candraw, H, H);
            step_e2_fb<<<B, 256, 0, stream>>>(candraw, S1, gammas, betas, z, h, out, t);
        }
    }
}

// Round 9
// 5120.750 us; speedup vs baseline: 3.8798x; 1.3256x over previous
//
#include <hip/hip_runtime.h>
#include <hip/hip_bf16.h>

#define EPSF 1e-5f

typedef unsigned short u16;
typedef unsigned int   u32;
typedef __attribute__((ext_vector_type(8))) short short8;
typedef __attribute__((ext_vector_type(4))) float f32x4;

constexpr int B  = 256;
constexpr int T  = 128;
constexpr int H  = 1024;
constexpr int INNER = 3 * H;   // 3072
constexpr int BT = B * T;      // 32768
constexpr int NZ = 2 * H;      // 2048

__device__ inline u16 f2bf(float v) {
    u32 u = __float_as_uint(v);
    return (u16)((u + 0x7fffu + ((u >> 16) & 1u)) >> 16);
}
__device__ inline float bf2f(u16 h) { return __uint_as_float(((u32)h) << 16); }

// ---------- one-time: transpose fp32 [1024][3072] -> split bf16 [3072][1024] ----------
__global__ __launch_bounds__(256)
void transpose_split(const float* __restrict__ src, u16* __restrict__ dhi, u16* __restrict__ dlo)
{
    __shared__ float tile[32][33];
    const int tx = threadIdx.x & 31, ty = threadIdx.x >> 5;
    const int bx = blockIdx.x, by = blockIdx.y;
    #pragma unroll
    for (int i = 0; i < 4; ++i)
        tile[ty + i * 8][tx] = src[(size_t)(by * 32 + ty + i * 8) * INNER + bx * 32 + tx];
    __syncthreads();
    #pragma unroll
    for (int i = 0; i < 4; ++i) {
        int n = bx * 32 + ty + i * 8;
        int k = by * 32 + tx;
        float v = tile[tx][ty + i * 8];
        u16 hi = f2bf(v);
        dhi[(size_t)n * H + k] = hi;
        dlo[(size_t)n * H + k] = f2bf(v - bf2f(hi));
    }
}

// ---------- big GEMM: S1b = x @ W + bias (fp32 out), split-bf16 3-pass MFMA ----------
// Tile 128x128, BK=64, on-the-fly split of A(fp32). B pre-split [N][K].
__global__ __launch_bounds__(256)
void gemm_s1(const float* __restrict__ Af,
             const u16* __restrict__ Bhi, const u16* __restrict__ Blo,
             const float* __restrict__ bias, float* __restrict__ C)
{
    constexpr int BM = 128, BN = 128, FM = 4, FN = 4;
    __shared__ char lds[(BM + BN) * 256];
    char* sAhi = lds;
    char* sAlo = lds + BM * 128;
    char* sBhi = lds + BM * 256;
    char* sBlo = lds + BM * 256 + BN * 128;

    const int tid = threadIdx.x;
    const int m0 = blockIdx.y * BM, n0 = blockIdx.x * BN;
    const int wid = tid >> 6, lane = tid & 63;
    const int wm = wid >> 1, wn = wid & 1;
    const int lr = lane & 15, kg = lane >> 4;

    f32x4 acc[FM][FN] = {};

    for (int k0 = 0; k0 < H; k0 += 64) {
        {
            constexpr int NC = BM * 16 / 256;   // 8
            #pragma unroll
            for (int i = 0; i < NC; ++i) {
                int c = tid + i * 256;
                int row = c >> 4, kc = c & 15;
                const float4 v = *(const float4*)(Af + (size_t)(m0 + row) * H + k0 + kc * 4);
                u16 h0 = f2bf(v.x), h1 = f2bf(v.y), h2 = f2bf(v.z), h3 = f2bf(v.w);
                u16 l0 = f2bf(v.x - bf2f(h0)), l1 = f2bf(v.y - bf2f(h1));
                u16 l2 = f2bf(v.z - bf2f(h2)), l3 = f2bf(v.w - bf2f(h3));
                uint2 hp, lp;
                hp.x = (u32)h0 | ((u32)h1 << 16); hp.y = (u32)h2 | ((u32)h3 << 16);
                lp.x = (u32)l0 | ((u32)l1 << 16); lp.y = (u32)l2 | ((u32)l3 << 16);
                int boff = row * 128 + ((((kc >> 1)) ^ (row & 7)) << 4) + ((kc & 1) << 3);
                *(uint2*)(sAhi + boff) = hp;
                *(uint2*)(sAlo + boff) = lp;
            }
        }
        {
            constexpr int NC = BN * 8 / 256;    // 4
            #pragma unroll
            for (int i = 0; i < NC; ++i) {
                int c = tid + i * 256;
                int row = c >> 3, kc = c & 7;
                int boff = row * 128 + ((kc ^ (row & 7)) << 4);
                *(float4*)(sBhi + boff) = *(const float4*)(Bhi + (size_t)(n0 + row) * H + k0 + kc * 8);
                *(float4*)(sBlo + boff) = *(const float4*)(Blo + (size_t)(n0 + row) * H + k0 + kc * 8);
            }
        }
        __syncthreads();

        #pragma unroll
        for (int ks = 0; ks < 2; ++ks) {
            short8 ah[FM], al[FM], bh[FN], bl[FN];
            #pragma unroll
            for (int mi = 0; mi < FM; ++mi) {
                int row = wm * FM * 16 + mi * 16 + lr;
                int off = row * 128 + ((((ks << 2) | kg) ^ (row & 7)) << 4);
                ah[mi] = *(const short8*)(sAhi + off);
                al[mi] = *(const short8*)(sAlo + off);
            }
            #pragma unroll
            for (int ni = 0; ni < FN; ++ni) {
                int row = wn * FN * 16 + ni * 16 + lr;
                int off = row * 128 + ((((ks << 2) | kg) ^ (row & 7)) << 4);
                bh[ni] = *(const short8*)(sBhi + off);
                bl[ni] = *(const short8*)(sBlo + off);
            }
            #pragma unroll
            for (int mi = 0; mi < FM; ++mi)
                #pragma unroll
                for (int ni = 0; ni < FN; ++ni) {
                    acc[mi][ni] = __builtin_amdgcn_mfma_f32_16x16x32_bf16(ah[mi], bh[ni], acc[mi][ni], 0, 0, 0);
                    acc[mi][ni] = __builtin_amdgcn_mfma_f32_16x16x32_bf16(ah[mi], bl[ni], acc[mi][ni], 0, 0, 0);
                    acc[mi][ni] = __builtin_amdgcn_mfma_f32_16x16x32_bf16(al[mi], bh[ni], acc[mi][ni], 0, 0, 0);
                }
        }
        __syncthreads();
    }

    #pragma unroll
    for (int ni = 0; ni < FN; ++ni) {
        int col = n0 + wn * FN * 16 + ni * 16 + lr;
        float bb = bias[col];
        #pragma unroll
        for (int mi = 0; mi < FM; ++mi) {
            #pragma unroll
            for (int r = 0; r < 4; ++r) {
                int row = m0 + wm * FM * 16 + mi * 16 + kg * 4 + r;
                C[(size_t)row * INNER + col] = acc[mi][ni][r] + bb;
            }
        }
    }
}

// ---------- pipaged step GEMM, BK=128 (half the barriers of BK=64), plain staging ----------
// 2D grid identical to round-5: blockIdx.x = n-tile, blockIdx.y = m-tile.
template<int BM, int BN, int FM, int FN>
__global__ __launch_bounds__(256)
void step_gemm(const u16* __restrict__ Ahi, const u16* __restrict__ Alo,
               const u16* __restrict__ Bhi, const u16* __restrict__ Blo,
               float* __restrict__ C, int ldc)
{
    constexpr int NWN = BN / (FN * 16);
    constexpr int NWM = BM / (FM * 16);
    static_assert(NWM * NWN == 4, "need 4 waves");
    constexpr int NCA = BM * 16 / 256;
    constexpr int NCB = BN * 16 / 256;
    __shared__ char lds[(BM + BN) * 512];
    char* sAhi = lds;
    char* sAlo = lds + BM * 256;
    char* sBhi = lds + BM * 512;
    char* sBlo = lds + BM * 512 + BN * 256;

    const int tid = threadIdx.x;
    const int m0 = blockIdx.y * BM, n0 = blockIdx.x * BN;
    const int wid = tid >> 6, lane = tid & 63;
    const int wm = wid / NWN, wn = wid % NWN;
    const int lr = lane & 15, kg = lane >> 4;

    f32x4 acc[FM][FN] = {};

    for (int k0 = 0; k0 < H; k0 += 128) {
        #pragma unroll
        for (int i = 0; i < NCA; ++i) {
            int c = tid + i * 256;
            int row = c >> 4, kc = c & 15;
            int boff = row * 256 + ((kc ^ (row & 7)) << 4);
            *(float4*)(sAhi + boff) = *(const float4*)(Ahi + (size_t)(m0 + row) * H + k0 + kc * 8);
            *(float4*)(sAlo + boff) = *(const float4*)(Alo + (size_t)(m0 + row) * H + k0 + kc * 8);
        }
        #pragma unroll
        for (int i = 0; i < NCB; ++i) {
            int c = tid + i * 256;
            int row = c >> 4, kc = c & 15;
            int boff = row * 256 + ((kc ^ (row & 7)) << 4);
            *(float4*)(sBhi + boff) = *(const float4*)(Bhi + (size_t)(n0 + row) * H + k0 + kc * 8);
            *(float4*)(sBlo + boff) = *(const float4*)(Blo + (size_t)(n0 + row) * H + k0 + kc * 8);
        }
        __syncthreads();

        #pragma unroll
        for (int ks = 0; ks < 4; ++ks) {
            short8 ah[FM], al[FM], bh[FN], bl[FN];
            #pragma unroll
            for (int mi = 0; mi < FM; ++mi) {
                int row = wm * FM * 16 + mi * 16 + lr;
                int off = row * 256 + ((((ks << 2) | kg) ^ (row & 7)) << 4);
                ah[mi] = *(const short8*)(sAhi + off);
                al[mi] = *(const short8*)(sAlo + off);
            }
            #pragma unroll
            for (int ni = 0; ni < FN; ++ni) {
                int row = wn * FN * 16 + ni * 16 + lr;
                int off = row * 256 + ((((ks << 2) | kg) ^ (row & 7)) << 4);
                bh[ni] = *(const short8*)(sBhi + off);
                bl[ni] = *(const short8*)(sBlo + off);
            }
            #pragma unroll
            for (int mi = 0; mi < FM; ++mi)
                #pragma unroll
                for (int ni = 0; ni < FN; ++ni) {
                    acc[mi][ni] = __builtin_amdgcn_mfma_f32_16x16x32_bf16(ah[mi], bh[ni], acc[mi][ni], 0, 0, 0);
                    acc[mi][ni] = __builtin_amdgcn_mfma_f32_16x16x32_bf16(ah[mi], bl[ni], acc[mi][ni], 0, 0, 0);
                    acc[mi][ni] = __builtin_amdgcn_mfma_f32_16x16x32_bf16(al[mi], bh[ni], acc[mi][ni], 0, 0, 0);
                }
        }
        __syncthreads();
    }

    #pragma unroll
    for (int mi = 0; mi < FM; ++mi)
        #pragma unroll
        for (int ni = 0; ni < FN; ++ni) {
            int col = n0 + wn * FN * 16 + ni * 16 + lr;
            #pragma unroll
            for (int r = 0; r < 4; ++r) {
                int row = m0 + wm * FM * 16 + mi * 16 + kg * 4 + r;
                C[(size_t)row * ldc + col] = acc[mi][ni][r];
            }
        }
}

// ---------- block reduce (sum, sumsq) over 256 threads ----------
__device__ inline void block_reduce2(float& s, float& sq, int tid) {
    #pragma unroll
    for (int off = 32; off > 0; off >>= 1) { s += __shfl_down(s, off); sq += __shfl_down(sq, off); }
    __shared__ float rs[4], rq[4];
    if ((tid & 63) == 0) { rs[tid >> 6] = s; rq[tid >> 6] = sq; }
    __syncthreads();
    s  = rs[0] + rs[1] + rs[2] + rs[3];
    sq = rq[0] + rq[1] + rq[2] + rq[3];
    __syncthreads();
}

// ---------- per-row LN stats over S1b rows of 3072 -> (mean, 1/denom) ----------
__global__ __launch_bounds__(256)
void ln_stats_v(const float* __restrict__ S1b, float* __restrict__ stat)
{
    const int row = blockIdx.x, tid = threadIdx.x;
    const float* p = S1b + (size_t)row * INNER;
    float s = 0.f, sq = 0.f;
    #pragma unroll
    for (int i = 0; i < 3; ++i) {
        float4 v = *(const float4*)(p + (tid + i * 256) * 4);
        s += v.x + v.y + v.z + v.w;
        sq += v.x*v.x + v.y*v.y + v.z*v.z + v.w*v.w;
    }
    block_reduce2(s, sq, tid);
    if (tid == 0) {
        float mean = s / (float)INNER;
        float var  = sq / (float)INNER - mean * mean;
        stat[row * 2 + 0] = mean;
        stat[row * 2 + 1] = 1.f / (sqrtf(var + EPSF) + EPSF);
    }
}

// ---------- step elementwise 1: LN(s2raw, 2048) + inline S1 LN -> z fp32, rh split ----------
__global__ __launch_bounds__(256)
void step_e1_v(const float* __restrict__ s2raw, const float* __restrict__ S1b,
               const float* __restrict__ stat, const float* __restrict__ h,
               const float* __restrict__ gammas, const float* __restrict__ betas,
               float* __restrict__ z, u16* __restrict__ rh_hi, u16* __restrict__ rh_lo, int t)
{
    const int b = blockIdx.x, tid = threadIdx.x;
    const float* row = s2raw + (size_t)b * NZ;
    float az[4], ar[4];
    {
        float4 vz = *(const float4*)(row + tid * 4);
        float4 vr = *(const float4*)(row + 1024 + tid * 4);
        az[0]=vz.x; az[1]=vz.y; az[2]=vz.z; az[3]=vz.w;
        ar[0]=vr.x; ar[1]=vr.y; ar[2]=vr.z; ar[3]=vr.w;
    }
    float s = 0.f, sq = 0.f;
    #pragma unroll
    for (int q = 0; q < 4; ++q) { s += az[q] + ar[q]; sq += az[q]*az[q] + ar[q]*ar[q]; }
    block_reduce2(s, sq, tid);
    const float mean = s / (float)NZ;
    const float var  = sq / (float)NZ - mean * mean;
    const float denom = sqrtf(var + EPSF) + EPSF;

    const size_t srow = (size_t)b * T + t;
    const float s1m = stat[srow * 2 + 0], s1r = stat[srow * 2 + 1];
    const float* s1 = S1b + srow * INNER;
    const int j0 = tid * 4;
    float4 zo;
    float* zp = (float*)&zo;
    #pragma unroll
    for (int q = 0; q < 4; ++q) {
        int j = j0 + q;
        float s1v = gammas[j] * (s1[j] - s1m) * s1r + betas[j];
        float ln  = gammas[INNER + j] * (az[q] - mean) / denom + betas[INNER + j];
        float sv  = 0.2f * (s1v + ln) + 0.5f;
        zp[q] = fminf(fmaxf(sv, 0.f), 1.f);
    }
    *(float4*)(z + (size_t)b * H + j0) = zo;

    uint2 hp, lp;
    u16 hh[4], ll[4];
    #pragma unroll
    for (int q = 0; q < 4; ++q) {
        int j = 1024 + j0 + q;
        float s1v = gammas[j] * (s1[j] - s1m) * s1r + betas[j];
        float ln  = gammas[INNER + j] * (ar[q] - mean) / denom + betas[INNER + j];
        float sv  = 0.2f * (s1v + ln) + 0.5f;
        sv = fminf(fmaxf(sv, 0.f), 1.f);
        float rv = sv * h[(size_t)b * H + j0 + q];
        hh[q] = f2bf(rv);
        ll[q] = f2bf(rv - bf2f(hh[q]));
    }
    hp.x = (u32)hh[0] | ((u32)hh[1] << 16); hp.y = (u32)hh[2] | ((u32)hh[3] << 16);
    lp.x = (u32)ll[0] | ((u32)ll[1] << 16); lp.y = (u32)ll[2] | ((u32)ll[3] << 16);
    *(uint2*)(rh_hi + (size_t)b * H + j0) = hp;
    *(uint2*)(rh_lo + (size_t)b * H + j0) = lp;
}

// ---------- step elementwise 2: LN(candraw, 1024) + inline S1 LN -> tanh -> h update ----------
__global__ __launch_bounds__(256)
void step_e2_v(const float* __restrict__ candraw, const float* __restrict__ S1b,
               const float* __restrict__ stat,
               const float* __restrict__ gammas, const float* __restrict__ betas,
               const float* __restrict__ z, float* __restrict__ h,
               u16* __restrict__ h_hi, u16* __restrict__ h_lo,
               float* __restrict__ out, int t)
{
    const int b = blockIdx.x, tid = threadIdx.x;
    float a[4];
    {
        float4 v = *(const float4*)(candraw + (size_t)b * H + tid * 4);
        a[0]=v.x; a[1]=v.y; a[2]=v.z; a[3]=v.w;
    }
    float s = a[0]+a[1]+a[2]+a[3];
    float sq = a[0]*a[0]+a[1]*a[1]+a[2]*a[2]+a[3]*a[3];
    block_reduce2(s, sq, tid);
    const float mean = s / (float)H;
    const float var  = sq / (float)H - mean * mean;
    const float denom = sqrtf(var + EPSF) + EPSF;

    const size_t srow = (size_t)b * T + t;
    const float s1m = stat[srow * 2 + 0], s1r = stat[srow * 2 + 1];
    const float* s1 = S1b + srow * INNER + NZ;
    const int j0 = tid * 4;
    float4 ho;
    float* hp_ = (float*)&ho;
    u16 hh[4], ll[4];
    #pragma unroll
    for (int q = 0; q < 4; ++q) {
        int j = j0 + q;
        float s1v = gammas[NZ + j] * (s1[j] - s1m) * s1r + betas[NZ + j];
        float ln  = gammas[INNER + NZ + j] * (a[q] - mean) / denom + betas[INNER + NZ + j];
        float cand = tanhf(s1v + ln);
        float zz = z[(size_t)b * H + j];
        float hold = h[(size_t)b * H + j];
        float hn = zz * hold + (1.f - zz) * cand;
        hp_[q] = hn;
        hh[q] = f2bf(hn);
        ll[q] = f2bf(hn - bf2f(hh[q]));
    }
    *(float4*)(h + (size_t)b * H + j0) = ho;
    uint2 hpck, lpck;
    hpck.x = (u32)hh[0] | ((u32)hh[1] << 16); hpck.y = (u32)hh[2] | ((u32)hh[3] << 16);
    lpck.x = (u32)ll[0] | ((u32)ll[1] << 16); lpck.y = (u32)ll[2] | ((u32)ll[3] << 16);
    *(uint2*)(h_hi + (size_t)b * H + j0) = hpck;
    *(uint2*)(h_lo + (size_t)b * H + j0) = lpck;
    *(float4*)(out + ((size_t)b * T + t) * H + j0) = ho;
}

// ================= fallback (validated fp32 path) =================
__global__ __launch_bounds__(256)
void ln_rows_v(float* __restrict__ S1, const float* __restrict__ bias,
               const float* __restrict__ gammas, const float* __restrict__ betas)
{
    const int row = blockIdx.x, tid = threadIdx.x;
    float* p = S1 + (size_t)row * INNER;
    float a[12];
    float s = 0.f, sq = 0.f;
    #pragma unroll
    for (int i = 0; i < 3; ++i) {
        int c = tid + i * 256;
        float4 v = *(const float4*)(p + c * 4);
        float4 bb = *(const float4*)(bias + c * 4);
        a[i*4+0] = v.x + bb.x; a[i*4+1] = v.y + bb.y; a[i*4+2] = v.z + bb.z; a[i*4+3] = v.w + bb.w;
        s += a[i*4+0] + a[i*4+1] + a[i*4+2] + a[i*4+3];
        sq += a[i*4+0]*a[i*4+0] + a[i*4+1]*a[i*4+1] + a[i*4+2]*a[i*4+2] + a[i*4+3]*a[i*4+3];
    }
    block_reduce2(s, sq, tid);
    const float mean = s / (float)INNER;
    const float var  = sq / (float)INNER - mean * mean;
    const float denom = sqrtf(var + EPSF) + EPSF;
    #pragma unroll
    for (int i = 0; i < 3; ++i) {
        int c = tid + i * 256;
        float4 o;
        o.x = gammas[c*4+0] * (a[i*4+0] - mean) / denom + betas[c*4+0];
        o.y = gammas[c*4+1] * (a[i*4+1] - mean) / denom + betas[c*4+1];
        o.z = gammas[c*4+2] * (a[i*4+2] - mean) / denom + betas[c*4+2];
        o.w = gammas[c*4+3] * (a[i*4+3] - mean) / denom + betas[c*4+3];
        *(float4*)(p + c * 4) = o;
    }
}

__global__ __launch_bounds__(256)
void gemm_fb(const float* __restrict__ A, int lda,
             const float* __restrict__ Bm, int ldb,
             float* __restrict__ C, int ldc, int K)
{
    constexpr int BM = 64, BN = 64, BK = 16;
    __shared__ float As[BK][BM];
    __shared__ float Bs[BK][BN];
    const int tid = threadIdx.x;
    const int tx = tid & 15, ty = tid >> 4;
    float acc[4][4] = {};
    const float* Ab = A + (size_t)blockIdx.y * BM * lda;
    const float* Bb = Bm + (size_t)blockIdx.x * BN;
    for (int k0 = 0; k0 < K; k0 += BK) {
        #pragma unroll
        for (int i = 0; i < 4; ++i) {
            int e = tid + i * 256; int m = e >> 4, k = e & 15;
            As[k][m] = Ab[(size_t)m * lda + k0 + k];
        }
        #pragma unroll
        for (int i = 0; i < 4; ++i) {
            int e = tid + i * 256; int k = e >> 6, n = e & 63;
            Bs[k][n] = Bb[(size_t)(k0 + k) * ldb + n];
        }
        __syncthreads();
        #pragma unroll
        for (int k = 0; k < BK; ++k) {
            float av[4], bv[4];
            #pragma unroll
            for (int i = 0; i < 4; ++i) av[i] = As[k][ty * 4 + i];
            #pragma unroll
            for (int j = 0; j < 4; ++j) bv[j] = Bs[k][tx * 4 + j];
            #pragma unroll
            for (int i = 0; i < 4; ++i)
                #pragma unroll
                for (int j = 0; j < 4; ++j)
                    acc[i][j] = fmaf(av[i], bv[j], acc[i][j]);
        }
        __syncthreads();
    }
    const int row0 = blockIdx.y * BM + ty * 4;
    const int col0 = blockIdx.x * BN + tx * 4;
    #pragma unroll
    for (int i = 0; i < 4; ++i)
        #pragma unroll
        for (int j = 0; j < 4; ++j)
            C[(size_t)(row0 + i) * ldc + col0 + j] = acc[i][j];
}

__global__ __launch_bounds__(256)
void step_e1_fb(const float* __restrict__ s2raw, const float* __restrict__ S1,
                const float* __restrict__ h,
                const float* __restrict__ gammas, const float* __restrict__ betas,
                float* __restrict__ z, float* __restrict__ rh, int t)
{
    const int b = blockIdx.x, tid = threadIdx.x;
    const float* row = s2raw + (size_t)b * NZ;
    float v[8]; float s = 0.f, sq = 0.f;
    #pragma unroll
    for (int i = 0; i < 8; ++i) { v[i] = row[tid + i * 256]; s += v[i]; sq += v[i]*v[i]; }
    block_reduce2(s, sq, tid);
    const float mean = s / (float)NZ;
    const float var  = sq / (float)NZ - mean * mean;
    const float denom = sqrtf(var + EPSF) + EPSF;
    const float* s1 = S1 + (size_t)(b * T + t) * INNER;
    #pragma unroll
    for (int i = 0; i < 8; ++i) {
        int j = tid + i * 256;
        float ln = gammas[INNER + j] * (v[i] - mean) / denom + betas[INNER + j];
        float sv = 0.2f * (s1[j] + ln) + 0.5f;
        sv = fminf(fmaxf(sv, 0.f), 1.f);
        if (j < H) z[(size_t)b * H + j] = sv;
        else       rh[(size_t)b * H + (j - H)] = sv * h[(size_t)b * H + (j - H)];
    }
}

__global__ __launch_bounds__(256)
void step_e2_fb(const float* __restrict__ candraw, const float* __restrict__ S1,
                const float* __restrict__ gammas, const float* __restrict__ betas,
                const float* __restrict__ z, float* __restrict__ h,
                float* __restrict__ out, int t)
{
    const int b = blockIdx.x, tid = threadIdx.x;
    float v[4]; float s = 0.f, sq = 0.f;
    #pragma unroll
    for (int i = 0; i < 4; ++i) { v[i] = candraw[(size_t)b * H + tid + i * 256]; s += v[i]; sq += v[i]*v[i]; }
    block_reduce2(s, sq, tid);
    const float mean = s / (float)H;
    const float var  = sq / (float)H - mean * mean;
    const float denom = sqrtf(var + EPSF) + EPSF;
    const float* s1 = S1 + (size_t)(b * T + t) * INNER + NZ;
    #pragma unroll
    for (int i = 0; i < 4; ++i) {
        int j = tid + i * 256;
        float ln = gammas[INNER + NZ + j] * (v[i] - mean) / denom + betas[INNER + NZ + j];
        float cand = tanhf(s1[j] + ln);
        float zz = z[(size_t)b * H + j];
        float hold = h[(size_t)b * H + j];
        float hn = zz * hold + (1.f - zz) * cand;
        h[(size_t)b * H + j] = hn;
        out[((size_t)b * T + t) * H + j] = hn;
    }
}

// ================= launch =================
extern "C" void kernel_launch(void* const* d_in, const int* in_sizes, int n_in,
                              void* d_out, int out_size, void* d_ws, size_t ws_size,
                              hipStream_t stream) {
    const float* x      = (const float*)d_in[0];
    const float* W      = (const float*)d_in[1];
    const float* U      = (const float*)d_in[2];
    const float* bias   = (const float*)d_in[3];
    const float* gammas = (const float*)d_in[4];
    const float* betas  = (const float*)d_in[5];
    float* out = (float*)d_out;
    (void)in_sizes; (void)n_in; (void)out_size;

    char* ws = (char*)d_ws;
    size_t off = 0;
    auto alloc = [&](size_t bytes) { void* p = ws + off; off += (bytes + 255) & ~(size_t)255; return p; };

    const size_t sz_S1 = (size_t)BT * INNER * 4;          // 402.7 MB
    const size_t sz_T  = (size_t)INNER * H * 2;           // 6.29 MB per split half
    const size_t sz_st = (size_t)BT * 2 * 4;              // 256 KB
    const size_t need_new = sz_S1 + 4 * sz_T + sz_st + ((size_t)B * H * 4) * 3 + (size_t)B * NZ * 4
                          + ((size_t)B * H * 2) * 4 + 16 * 1024;   // ~435.5 MB

    if (ws_size >= need_new) {
        float* S1b   = (float*)alloc(sz_S1);
        u16* WT_hi   = (u16*)alloc(sz_T);
        u16* WT_lo   = (u16*)alloc(sz_T);
        u16* UT_hi   = (u16*)alloc(sz_T);
        u16* UT_lo   = (u16*)alloc(sz_T);
        float* stat  = (float*)alloc(sz_st);
        float* h     = (float*)alloc((size_t)B * H * 4);
        float* z     = (float*)alloc((size_t)B * H * 4);
        float* s2raw = (float*)alloc((size_t)B * NZ * 4);
        float* candraw = (float*)alloc((size_t)B * H * 4);
        u16* h_hi    = (u16*)alloc((size_t)B * H * 2);
        u16* h_lo    = (u16*)alloc((size_t)B * H * 2);
        u16* rh_hi   = (u16*)alloc((size_t)B * H * 2);
        u16* rh_lo   = (u16*)alloc((size_t)B * H * 2);

        transpose_split<<<dim3(INNER / 32, H / 32), 256, 0, stream>>>(W, WT_hi, WT_lo);
        transpose_split<<<dim3(INNER / 32, H / 32), 256, 0, stream>>>(U, UT_hi, UT_lo);

        // S1b = x @ W + bias (raw, pre-LN); per-row stats separately; LN applied inline in e1/e2
        gemm_s1<<<dim3(INNER / 128, BT / 128), 256, 0, stream>>>(x, WT_hi, WT_lo, bias, S1b);
        ln_stats_v<<<BT, 256, 0, stream>>>(S1b, stat);

        hipMemsetAsync(h,    0, (size_t)B * H * 4, stream);
        hipMemsetAsync(h_hi, 0, (size_t)B * H * 2, stream);
        hipMemsetAsync(h_lo, 0, (size_t)B * H * 2, stream);

        const u16* Uc_hi = UT_hi + (size_t)NZ * H;
        const u16* Uc_lo = UT_lo + (size_t)NZ * H;

        for (int t = 0; t < T; ++t) {
            // G1: s2raw = h @ Uzr^T   (32x64 tiles, grid (32,8) as round 5, BK=128)
            step_gemm<32, 64, 1, 2><<<dim3(NZ / 64, B / 32), 256, 0, stream>>>(
                h_hi, h_lo, UT_hi, UT_lo, s2raw, NZ);
            step_e1_v<<<B, 256, 0, stream>>>(s2raw, S1b, stat, h, gammas, betas,
                                             z, rh_hi, rh_lo, t);
            // G2: candraw = rh @ Uc^T (32x32 tiles, grid (32,8), BK=128)
            step_gemm<32, 32, 1, 1><<<dim3(H / 32, B / 32), 256, 0, stream>>>(
                rh_hi, rh_lo, Uc_hi, Uc_lo, candraw, H);
            step_e2_v<<<B, 256, 0, stream>>>(candraw, S1b, stat, gammas, betas,
                                             z, h, h_hi, h_lo, out, t);
        }
    } else {
        // fallback: validated fp32 path
        float* S1    = (float*)alloc(sz_S1);
        float* h     = (float*)alloc((size_t)B * H * 4);
        float* z     = (float*)alloc((size_t)B * H * 4);
        float* rh    = (float*)alloc((size_t)B * H * 4);
        float* s2raw = (float*)alloc((size_t)B * NZ * 4);
        float* candraw = (float*)alloc((size_t)B * H * 4);

        hipMemsetAsync(h, 0, (size_t)B * H * 4, stream);
        gemm_fb<<<dim3(INNER / 64, BT / 64), 256, 0, stream>>>(x, H, W, INNER, S1, INNER, H);
        ln_rows_v<<<BT, 256, 0, stream>>>(S1, bias, gammas, betas);
        for (int t = 0; t < T; ++t) {
            gemm_fb<<<dim3(NZ / 64, B / 64), 256, 0, stream>>>(h, H, U, INNER, s2raw, NZ, H);
            step_e1_fb<<<B, 256, 0, stream>>>(s2raw, S1, h, gammas, betas, z, rh, t);
            gemm_fb<<<dim3(H / 64, B / 64), 256, 0, stream>>>(rh, H, U + NZ, INNER, candraw, H, H);
            step_e2_fb<<<B, 256, 0, stream>>>(candraw, S1, gammas, betas, z, h, out, t);
        }
    }
}